// Round 8
// baseline (1323.631 us; speedup 1.0000x reference)
//
#include <hip/hip_runtime.h>

typedef unsigned short u16;
typedef unsigned int   u32;
typedef unsigned long long u64;
typedef short    s8v  __attribute__((ext_vector_type(8)));   // 8 x bf16 bits
typedef float    f4v  __attribute__((ext_vector_type(4)));
typedef u64      ul2v __attribute__((ext_vector_type(2)));
typedef _Float16 h2v  __attribute__((ext_vector_type(2)));

#define DEV __device__ __forceinline__

DEV u16 f2bf(float f) {                       // fp32 -> bf16 (round-half-up)
  u32 u = __builtin_bit_cast(u32, f);
  return (u16)((u + 0x8000u) >> 16);
}
DEV float bf2f(u16 b) { u32 u = ((u32)b) << 16; return __builtin_bit_cast(float, u); }
DEV void splitbf(float f, u16& hi, u16& lo) { // f ~= hi + lo (bf16 pair)
  hi = f2bf(f);
  lo = f2bf(f - bf2f(hi));
}
DEV u16 f2h(float f) {                        // fp32 -> fp16 bits (RNE)
  _Float16 h = (_Float16)f;
  return __builtin_bit_cast(u16, h);
}
DEV float h2f(u16 b) { _Float16 h = __builtin_bit_cast(_Float16, b); return (float)h; }
DEV float fdot2u(u32 a, u32 b, float c) {     // half2 dot + acc (fp32)
#if __has_builtin(__builtin_amdgcn_fdot2)
  return __builtin_amdgcn_fdot2(__builtin_bit_cast(h2v, a),
                                __builtin_bit_cast(h2v, b), c, false);
#else
  h2v x = __builtin_bit_cast(h2v, a), y = __builtin_bit_cast(h2v, b);
  return c + (float)x[0]*(float)y[0] + (float)x[1]*(float)y[1];
#endif
}
DEV float sigm(float x) { return 1.f / (1.f + __expf(-x)); }
DEV f4v mfma16(s8v a, s8v b, f4v c) {
  return __builtin_amdgcn_mfma_f32_16x16x32_bf16(a, b, c, 0, 0, 0);
}

// ---------------- prep: split-bf16 weight conversions ----------------
__global__ void prep_k(const float* __restrict__ w1, const float* __restrict__ w2,
                       const float* __restrict__ fcw, const float* __restrict__ wih,
                       const float* __restrict__ whh, const float* __restrict__ bih,
                       const float* __restrict__ bhh,
                       u16* __restrict__ w1h, u16* __restrict__ w1l,
                       u16* __restrict__ w2h, u16* __restrict__ w2l,
                       u16* __restrict__ fh,  u16* __restrict__ fl,
                       u16* __restrict__ ih,  u16* __restrict__ il,
                       u16* __restrict__ whhh, float* __restrict__ bsum) {
  const int i0 = blockIdx.x * 256 + threadIdx.x;
  const int st = gridDim.x * 256;
  for (int i = i0; i < 663552; i += st) splitbf(fcw[i], fh[i], fl[i]);
  for (int i = i0; i < 262144; i += st) splitbf(wih[i], ih[i], il[i]);
  for (int i = i0; i < 262144; i += st) whhh[i] = f2h(whh[i]);
  for (int i = i0; i < 4096;   i += st) splitbf(w1[i], w1h[i], w1l[i]);
  for (int i = i0; i < 8192;   i += st) {
    const int oc = i >> 8, k = i & 255;
    const int ky = k >> 6, kx = (k >> 4) & 3, cc = k & 15;   // k = ky*64+kx*16+c
    splitbf(w2[((oc * 16 + cc) * 4 + ky) * 4 + kx], w2h[i], w2l[i]);
  }
  for (int i = i0; i < 1024; i += st) bsum[i] = bih[i] + bhh[i];
}

// ---------------- fused conv1 + conv2 (split-bf16 MFMA) ----------------
// One image per block, CHANNEL-PHASED conv1: stage one input channel
// (28.2 KB hi+lo bf16) in LDS at a time, coalesced + split ONCE per pixel,
// and accumulate conv1's K=256 across 4 phases into persistent per-chunk
// register accumulators (statically indexed acc[7] — rule #20). This fixes
// R7's direct-global version (4x redundant split VALU + 50% cache-line
// waste + >L1 footprint -> ~660us) while keeping LDS small enough for
// 2 blocks/CU (75.2 KB total vs R6's 149 KB -> 1 block/CU, latency-bound).
// t1 stride 24 u16 (4-way max bank aliasing); conv1 LDS frag reads are
// overlap-broadcast conflict-free.
__global__ __launch_bounds__(256) void convs_k(const float* __restrict__ obs,
    const u16* __restrict__ w1h, const u16* __restrict__ w1l, const float* __restrict__ b1,
    const u16* __restrict__ w2h, const u16* __restrict__ w2l, const float* __restrict__ b2,
    u16* __restrict__ out2h, u16* __restrict__ out2l) {
  __shared__ __align__(16) u16 imgh[7056], imgl[7056];       // 1 channel, 28.2 KB
  __shared__ __align__(16) u16 t1h[400 * 24], t1l[400 * 24]; // conv1 out, 38.4 KB
  __shared__ __align__(16) u16 t2h[2592], t2l[2592];         // conv2 out, 10.4 KB
  const int tid = threadIdx.x;
  const int lane = tid & 63;
  const int wid = tid >> 6;
  const int l15 = lane & 15, kc = lane >> 4;
  const int n = blockIdx.x;
  // conv1 weights resident in regs (64 VGPRs); k0 = c*2+ks chunk index
  s8v bw1h[8], bw1l[8];
  #pragma unroll
  for (int k0 = 0; k0 < 8; ++k0) {
    const int o1 = l15 * 256 + k0 * 32 + kc * 8;
    bw1h[k0] = *(const s8v*)(w1h + o1);
    bw1l[k0] = *(const s8v*)(w1l + o1);
  }
  const float bias1 = b1[l15];
  const float bb2a = b2[l15], bb2b = b2[16 + l15];
  const float* img = obs + (u64)n * 28224;
  // persistent conv1 accumulators: 7 chunks/wave (ch = wid + cc*4 < 25)
  f4v ahh[7], ahl[7], alh[7];
  #pragma unroll
  for (int cc = 0; cc < 7; ++cc) {
    ahh[cc] = f4v{0,0,0,0}; ahl[cc] = f4v{0,0,0,0}; alh[cc] = f4v{0,0,0,0};
  }
  #pragma unroll
  for (int c = 0; c < 4; ++c) {
    __syncthreads();                        // img consumed by previous phase
    // stage channel c -> hi/lo bf16 LDS (coalesced, each pixel once)
    const float4* src = (const float4*)(img + c * 7056);
    #pragma unroll
    for (int e = 0; e < 7; ++e) {
      const int idx = e * 256 + tid;        // 1764 float4 = 7056 px
      if (idx < 1764) {
        float4 v = src[idx];
        u16 h0, l0, h1, l1, h2, l2, h3, l3;
        splitbf(v.x, h0, l0); splitbf(v.y, h1, l1);
        splitbf(v.z, h2, l2); splitbf(v.w, h3, l3);
        uint2 ph, pl;
        ph.x = (u32)h0 | ((u32)h1 << 16); ph.y = (u32)h2 | ((u32)h3 << 16);
        pl.x = (u32)l0 | ((u32)l1 << 16); pl.y = (u32)l2 | ((u32)l3 << 16);
        *(uint2*)(&imgh[idx * 4]) = ph;
        *(uint2*)(&imgl[idx * 4]) = pl;
      }
    }
    __syncthreads();
    // conv1 partial K (this channel = 2 MFMA k-steps)
    #pragma unroll
    for (int cc = 0; cc < 7; ++cc) {
      const int ch = wid + cc * 4;          // wave-uniform
      if (ch < 25) {
        const int p = ch * 16 + l15;
        const int oy = p / 20, ox = p - oy * 20;
        const int base = oy * 336 + ox * 4; // (4*oy)*84 + 4*ox within channel
        #pragma unroll
        for (int ks = 0; ks < 2; ++ks) {
          const int ky = ks * 4 + kc;       // k_local = ks*32 + kc*8 + kx
          const int off = base + ky * 84;
          ul2v th, tl;
          th[0] = *(const u64*)(imgh + off); th[1] = *(const u64*)(imgh + off + 4);
          tl[0] = *(const u64*)(imgl + off); tl[1] = *(const u64*)(imgl + off + 4);
          s8v Ah = __builtin_bit_cast(s8v, th), Al = __builtin_bit_cast(s8v, tl);
          const int k0 = c * 2 + ks;
          ahh[cc] = mfma16(Ah, bw1h[k0], ahh[cc]);
          ahl[cc] = mfma16(Ah, bw1l[k0], ahl[cc]);
          alh[cc] = mfma16(Al, bw1h[k0], alh[cc]);
        }
      }
    }
  }
  // t1 write (relu + re-split); no barrier needed before (t1 disjoint of img)
  #pragma unroll
  for (int cc = 0; cc < 7; ++cc) {
    const int ch = wid + cc * 4;
    if (ch < 25) {
      const int pr0 = ch * 16 + (lane >> 4) * 4;
      #pragma unroll
      for (int r = 0; r < 4; ++r) {
        float v = fmaxf(ahh[cc][r] + ahl[cc][r] + alh[cc][r] + bias1, 0.f);
        u16 hi, lo; splitbf(v, hi, lo);
        t1h[(pr0 + r) * 24 + l15] = hi;
        t1l[(pr0 + r) * 24 + l15] = lo;
      }
    }
  }
  __syncthreads();
  // conv2 (stride 2, 4x4): 6 chunks x 2 oc-tiles (81 positions padded to 96)
  for (int u = wid; u < 12; u += 4) {
    const int ch = u >> 1, ot = u & 1;      // ot fixed per wave
    const int p = ch * 16 + l15;
    const int pc = p < 81 ? p : 80;
    const int oy = pc / 9, ox = pc - oy * 9;
    const int base = (oy * 40 + ox * 2) * 24;
    f4v ahh2 = {0,0,0,0}, ahl2 = {0,0,0,0}, alh2 = {0,0,0,0};
    #pragma unroll
    for (int k0 = 0; k0 < 8; ++k0) {
      const int kb = k0 * 32 + kc * 8;      // k = ky*64 + kx*16 + c
      const int ky = kb >> 6, kx = (kb >> 4) & 3, c0 = kb & 15;
      const int off = base + (ky * 20 + kx) * 24 + c0;
      s8v Ah = *(const s8v*)(t1h + off);
      s8v Al = *(const s8v*)(t1l + off);
      const int wo = (ot * 16 + l15) * 256 + k0 * 32 + kc * 8;
      s8v Bh = *(const s8v*)(w2h + wo);
      s8v Bl = *(const s8v*)(w2l + wo);
      ahh2 = mfma16(Ah, Bh, ahh2);
      ahl2 = mfma16(Ah, Bl, ahl2);
      alh2 = mfma16(Al, Bh, alh2);
    }
    const float bb = ot ? bb2b : bb2a;
    const int oc = ot * 16 + l15;
    const int pr0 = ch * 16 + (lane >> 4) * 4;
    #pragma unroll
    for (int r = 0; r < 4; ++r) {
      const int pp = pr0 + r;
      if (pp < 81) {
        float v = fmaxf(ahh2[r] + ahl2[r] + alh2[r] + bb, 0.f);
        u16 hi, lo; splitbf(v, hi, lo);
        t2h[oc * 81 + pp] = hi;
        t2l[oc * 81 + pp] = lo;
      }
    }
  }
  __syncthreads();
  // t2 -> out2[n][2592] (flat order c*81 + oy*9 + ox, matches fc_w)
  {
    u32* dh = (u32*)(out2h + (u64)n * 2592);
    u32* dl = (u32*)(out2l + (u64)n * 2592);
    const u32* sh = (const u32*)t2h;
    const u32* sl = (const u32*)t2l;
    for (int e = tid; e < 1296; e += 256) { dh[e] = sh[e]; dl[e] = sl[e]; }
  }
}

// ------- split-bf16 GEMM: C = A(MxK) * B(NxK)^T, A~Ah+Al, B~Bh+Bl -------
// BM=BN=128, BK=32, 4 waves (2x2), each wave 64x64 via 4x4 16x16x32 MFMA
template <int RELU, int OSPLIT>
__global__ __launch_bounds__(256) void gemm3_k(const u16* __restrict__ Ah,
    const u16* __restrict__ Al, const u16* __restrict__ Bh, const u16* __restrict__ Bl,
    const float* __restrict__ bias, void* __restrict__ o1, void* __restrict__ o2,
    int M, int N, int K) {
  __shared__ __align__(16) u16 lAh[4096], lAl[4096];  // [128][32]
  __shared__ __align__(16) u16 lBh[4096], lBl[4096];  // [128][32]
  const int tid = threadIdx.x, lane = tid & 63, wid = tid >> 6;
  const int nb = N >> 7;
  const int bm = (int)blockIdx.x / nb, bn = (int)blockIdx.x % nb;
  const int m0 = bm << 7, n0 = bn << 7;
  const int wr = wid >> 1, wc = wid & 1;
  const int l15 = lane & 15, l4 = lane >> 4;
  f4v acc[4][4] = {};
  const int srow = tid >> 2;
  const int scol = (tid & 3) << 3;
  const u64 rA0 = (u64)(m0 + srow) * K + scol;
  const u64 rA1 = (u64)(m0 + 64 + srow) * K + scol;
  const u64 rB0 = (u64)(n0 + srow) * K + scol;
  const u64 rB1 = (u64)(n0 + 64 + srow) * K + scol;
  for (int k0 = 0; k0 < K; k0 += 32) {
    uint4 vah0 = *(const uint4*)(Ah + rA0 + k0);
    uint4 vah1 = *(const uint4*)(Ah + rA1 + k0);
    uint4 val0 = *(const uint4*)(Al + rA0 + k0);
    uint4 val1 = *(const uint4*)(Al + rA1 + k0);
    uint4 vbh0 = *(const uint4*)(Bh + rB0 + k0);
    uint4 vbh1 = *(const uint4*)(Bh + rB1 + k0);
    uint4 vbl0 = *(const uint4*)(Bl + rB0 + k0);
    uint4 vbl1 = *(const uint4*)(Bl + rB1 + k0);
    __syncthreads();
    ((uint4*)lAh)[tid] = vah0;  ((uint4*)lAh)[256 + tid] = vah1;
    ((uint4*)lAl)[tid] = val0;  ((uint4*)lAl)[256 + tid] = val1;
    ((uint4*)lBh)[tid] = vbh0;  ((uint4*)lBh)[256 + tid] = vbh1;
    ((uint4*)lBl)[tid] = vbl0;  ((uint4*)lBl)[256 + tid] = vbl1;
    __syncthreads();
    s8v afh[4], afl[4], bfh[4], bfl[4];
    #pragma unroll
    for (int a = 0; a < 4; ++a) {
      const int off = (wr * 64 + a * 16 + l15) * 32 + l4 * 8;
      afh[a] = *(const s8v*)(lAh + off);
      afl[a] = *(const s8v*)(lAl + off);
    }
    #pragma unroll
    for (int b = 0; b < 4; ++b) {
      const int off = (wc * 64 + b * 16 + l15) * 32 + l4 * 8;
      bfh[b] = *(const s8v*)(lBh + off);
      bfl[b] = *(const s8v*)(lBl + off);
    }
    #pragma unroll
    for (int a = 0; a < 4; ++a)
      #pragma unroll
      for (int b = 0; b < 4; ++b) {
        acc[a][b] = mfma16(afh[a], bfh[b], acc[a][b]);
        acc[a][b] = mfma16(afh[a], bfl[b], acc[a][b]);
        acc[a][b] = mfma16(afl[a], bfh[b], acc[a][b]);
      }
  }
  #pragma unroll
  for (int a = 0; a < 4; ++a) {
    const int mr = m0 + wr * 64 + a * 16 + l4 * 4;
    #pragma unroll
    for (int b = 0; b < 4; ++b) {
      const int col = n0 + wc * 64 + b * 16 + l15;
      const float bv = bias[col];
      #pragma unroll
      for (int r = 0; r < 4; ++r) {
        float v = acc[a][b][r] + bv;
        if (RELU) v = fmaxf(v, 0.f);
        const u64 idx = (u64)(mr + r) * N + col;
        if (OSPLIT) {
          u16 hi, lo; splitbf(v, hi, lo);
          ((u16*)o1)[idx] = hi;
          ((u16*)o2)[idx] = lo;
        } else {
          ((float*)o1)[idx] = v;
        }
      }
    }
  }
}

// ---------------- LSTM scan: 1 workgroup (1024 thr) per batch element ----
// thread (col=t&255, kq=t>>8) owns the K-QUARTER [kq*64, kq*64+64) of gate
// rows col (i), 256+col (f), 512+col (g) in VGPRs: 3 gates x 8 uint4 = 96
// VGPRs of weights — fits the 128-VGPR cap the compiler grants 1024-thread
// blocks (R4/R5 lesson: design to the cap instead of fighting it). o-gate
// rows in LDS chunk-transposed [kp4][col] (measured: 0 bank conflicts).
// h carried as fp16 hi+lo pair (fp32-grade). K-quarter partials reduced
// via 12 KB LDS. kq is wave-uniform -> divergence-free.
__global__ __launch_bounds__(1024) void lstm_k(const float* __restrict__ pre,
    const float* __restrict__ mask, const float* __restrict__ h0,
    const float* __restrict__ c0, const u16* __restrict__ whh,
    float* __restrict__ hs) {
  __shared__ __align__(16) uint4 lds_o[32 * 256];   // [kp4][col], 128 KB
  __shared__ __align__(16) float4 lds_red[3 * 256]; // kq=1..3 partials, 12 KB
  __shared__ __align__(16) u32 lds_hh[128];         // h hi (fp16 pairs)
  __shared__ __align__(16) u32 lds_hl[128];         // h lo
  const int t = threadIdx.x, b = blockIdx.x;
  const int col = t & 255, kq = t >> 8;             // kq wave-uniform
  // gate-row weights, K-quarter each: 8 uint4 per gate = 96 VGPRs total
  uint4 wi[8], wf[8], wg[8];
  {
    const u32* wb = (const u32*)whh;
    const uint4* pi_ = (const uint4*)(wb + (u64)col * 128) + kq * 8;
    const uint4* pf_ = (const uint4*)(wb + (u64)(256 + col) * 128) + kq * 8;
    const uint4* pg_ = (const uint4*)(wb + (u64)(512 + col) * 128) + kq * 8;
    #pragma unroll
    for (int q = 0; q < 8; ++q) {
      wi[q] = pi_[q]; wf[q] = pf_[q]; wg[q] = pg_[q];
    }
    // o-gate row quarter -> LDS chunk-transposed
    const uint4* po_ = (const uint4*)(wb + (u64)(768 + col) * 128);
    #pragma unroll
    for (int j = 0; j < 8; ++j) {
      const int kp4 = kq * 8 + j;
      lds_o[kp4 * 256 + col] = po_[kp4];
    }
  }
  float c = 0.f;
  if (kq == 0) c = c0[b * 256 + col];
  if (t < 128) {
    float a0 = h0[b * 256 + 2 * t], a1 = h0[b * 256 + 2 * t + 1];
    u16 h0a = f2h(a0); u16 l0a = f2h(a0 - h2f(h0a));
    u16 h1a = f2h(a1); u16 l1a = f2h(a1 - h2f(h1a));
    lds_hh[t] = (u32)h0a | ((u32)h1a << 16);
    lds_hl[t] = (u32)l0a | ((u32)l1a << 16);
  }
  float npi = 0.f, npf = 0.f, npg = 0.f, npo = 0.f;
  if (kq == 0) {                                    // prefetch step-0 pre
    const float* pr = pre + (u64)b * 1024;
    npi = pr[col]; npf = pr[256 + col]; npg = pr[512 + col]; npo = pr[768 + col];
  }
  __syncthreads();
  for (int s = 0; s < 80; ++s) {
    float ai = npi, afv = npf, ag = npg, ao = npo;  // kq!=0: zeros (partials)
    #pragma unroll
    for (int j = 0; j < 8; ++j) {
      const int kk = kq * 8 + j;
      const uint4 ov = lds_o[kk * 256 + col];       // conflict-free
      const uint4 hh = ((const uint4*)lds_hh)[kk];  // broadcast
      const uint4 hl = ((const uint4*)lds_hl)[kk];  // broadcast
      ai  = fdot2u(wi[j].x, hh.x, ai);  ai  = fdot2u(wi[j].y, hh.y, ai);
      ai  = fdot2u(wi[j].z, hh.z, ai);  ai  = fdot2u(wi[j].w, hh.w, ai);
      ai  = fdot2u(wi[j].x, hl.x, ai);  ai  = fdot2u(wi[j].y, hl.y, ai);
      ai  = fdot2u(wi[j].z, hl.z, ai);  ai  = fdot2u(wi[j].w, hl.w, ai);
      afv = fdot2u(wf[j].x, hh.x, afv); afv = fdot2u(wf[j].y, hh.y, afv);
      afv = fdot2u(wf[j].z, hh.z, afv); afv = fdot2u(wf[j].w, hh.w, afv);
      afv = fdot2u(wf[j].x, hl.x, afv); afv = fdot2u(wf[j].y, hl.y, afv);
      afv = fdot2u(wf[j].z, hl.z, afv); afv = fdot2u(wf[j].w, hl.w, afv);
      ag  = fdot2u(wg[j].x, hh.x, ag);  ag  = fdot2u(wg[j].y, hh.y, ag);
      ag  = fdot2u(wg[j].z, hh.z, ag);  ag  = fdot2u(wg[j].w, hh.w, ag);
      ag  = fdot2u(wg[j].x, hl.x, ag);  ag  = fdot2u(wg[j].y, hl.y, ag);
      ag  = fdot2u(wg[j].z, hl.z, ag);  ag  = fdot2u(wg[j].w, hl.w, ag);
      ao  = fdot2u(ov.x, hh.x, ao);     ao  = fdot2u(ov.y, hh.y, ao);
      ao  = fdot2u(ov.z, hh.z, ao);     ao  = fdot2u(ov.w, hh.w, ao);
      ao  = fdot2u(ov.x, hl.x, ao);     ao  = fdot2u(ov.y, hl.y, ao);
      ao  = fdot2u(ov.z, hl.z, ao);     ao  = fdot2u(ov.w, hl.w, ao);
    }
    if (kq != 0) {
      float4 r; r.x = ai; r.y = afv; r.z = ag; r.w = ao;
      lds_red[(kq - 1) * 256 + col] = r;
    } else if (s + 1 < 80) {                        // prefetch next-step pre
      const float* pr = pre + (u64)((s + 1) * 128 + b) * 1024;
      npi = pr[col]; npf = pr[256 + col]; npg = pr[512 + col]; npo = pr[768 + col];
    }
    __syncthreads();
    if (kq == 0) {
      const float4 r1 = lds_red[col];
      const float4 r2 = lds_red[256 + col];
      const float4 r3 = lds_red[512 + col];
      ai += r1.x + r2.x + r3.x;
      afv += r1.y + r2.y + r3.y;
      ag += r1.z + r2.z + r3.z;
      ao += r1.w + r2.w + r3.w;
      const float m = mask[s * 128 + b];
      const float ig = sigm(ai), fg = sigm(afv), og = sigm(ao);
      const float gg = tanhf(ag);
      const float cn = fg * c + ig * gg;
      const float hn = og * tanhf(cn);
      hs[(u64)(s * 128 + b) * 256 + col] = hn;      // unmasked output
      c = cn * m;
      const float hm = hn * m;                      // masked carry
      u16 hhi = f2h(hm);
      u16 hlo = f2h(hm - h2f(hhi));
      ((u16*)lds_hh)[col] = hhi;
      ((u16*)lds_hl)[col] = hlo;
    }
    __syncthreads();
  }
}

// ---------------- heads: value, log-softmax, entropy, action gather -------
__global__ __launch_bounds__(256) void heads_k(const float* __restrict__ hs,
    const float* __restrict__ vw, const float* __restrict__ vb,
    const float* __restrict__ lw, const float* __restrict__ lb,
    const int* __restrict__ acts, float* __restrict__ out) {
  const int lane = threadIdx.x & 63, wid = threadIdx.x >> 6;
  const int row = blockIdx.x * 4 + wid;
  const float4 h4 = *(const float4*)(hs + (u64)row * 256 + lane * 4);
  float lj[18];
  #pragma unroll
  for (int j = 0; j < 18; ++j) {
    const float4 w4 = *(const float4*)(lw + j * 256 + lane * 4);
    float p = h4.x * w4.x + h4.y * w4.y + h4.z * w4.z + h4.w * w4.w;
    #pragma unroll
    for (int o = 32; o > 0; o >>= 1) p += __shfl_xor(p, o, 64);
    lj[j] = p + lb[j];
  }
  const float4 v4 = *(const float4*)(vw + lane * 4);
  float val = h4.x * v4.x + h4.y * v4.y + h4.z * v4.z + h4.w * v4.w;
  #pragma unroll
  for (int o = 32; o > 0; o >>= 1) val += __shfl_xor(val, o, 64);
  val += vb[0];
  float mx = lj[0];
  #pragma unroll
  for (int j = 1; j < 18; ++j) mx = fmaxf(mx, lj[j]);
  float sum = 0.f;
  #pragma unroll
  for (int j = 0; j < 18; ++j) sum += __expf(lj[j] - mx);
  const float ls = __logf(sum);
  const int a = acts[row];
  float tlp = 0.f, ent = 0.f;
  #pragma unroll
  for (int j = 0; j < 18; ++j) {
    const float lp = lj[j] - mx - ls;
    const float pj = __expf(lp);
    ent -= pj * lp;
    if (j == a) tlp = lp;
  }
  if (lane == 0) {
    out[row]         = tlp;
    out[10240 + row] = ent;
    out[20480 + row] = val;
  }
}

// ---------------- launch ----------------
extern "C" void kernel_launch(void* const* d_in, const int* in_sizes, int n_in,
                              void* d_out, int out_size, void* d_ws, size_t ws_size,
                              hipStream_t stream) {
  const float* obs  = (const float*)d_in[0];
  const float* mask = (const float*)d_in[1];
  const float* h0   = (const float*)d_in[2];
  const float* c0   = (const float*)d_in[3];
  const int*   acts = (const int*)d_in[4];
  const float* w1   = (const float*)d_in[5];
  const float* b1   = (const float*)d_in[6];
  const float* w2   = (const float*)d_in[7];
  const float* b2   = (const float*)d_in[8];
  const float* fcw  = (const float*)d_in[9];
  const float* fcb  = (const float*)d_in[10];
  const float* wih  = (const float*)d_in[11];
  const float* whh  = (const float*)d_in[12];
  const float* bih  = (const float*)d_in[13];
  const float* bhh  = (const float*)d_in[14];
  const float* vw   = (const float*)d_in[15];
  const float* vb   = (const float*)d_in[16];
  const float* lw   = (const float*)d_in[17];
  const float* lb   = (const float*)d_in[18];
  float* out = (float*)d_out;

  char* cur = (char*)d_ws;
  auto carve = [&](size_t bytes) {
    void* p = cur; cur += (bytes + 255) & ~(size_t)255; return p;
  };
  u16*   out2h = (u16*)carve(10240ULL * 2592 * 2);
  u16*   out2l = (u16*)carve(10240ULL * 2592 * 2);
  u16*   xh    = (u16*)carve(10240ULL * 256 * 2);
  u16*   xl    = (u16*)carve(10240ULL * 256 * 2);
  float* pre   = (float*)carve(10240ULL * 1024 * 4);
  float* hs    = (float*)carve(10240ULL * 256 * 4);
  u16*   w1h   = (u16*)carve(4096ULL * 2);
  u16*   w1l   = (u16*)carve(4096ULL * 2);
  u16*   w2h   = (u16*)carve(8192ULL * 2);
  u16*   w2l   = (u16*)carve(8192ULL * 2);
  u16*   fwh   = (u16*)carve(663552ULL * 2);
  u16*   fwl   = (u16*)carve(663552ULL * 2);
  u16*   iwh   = (u16*)carve(262144ULL * 2);
  u16*   iwl   = (u16*)carve(262144ULL * 2);
  u16*   whhh  = (u16*)carve(262144ULL * 2);
  float* bsum  = (float*)carve(1024ULL * 4);

  prep_k<<<512, 256, 0, stream>>>(w1, w2, fcw, wih, whh, bih, bhh,
                                  w1h, w1l, w2h, w2l, fwh, fwl, iwh, iwl, whhh, bsum);
  convs_k<<<10240, 256, 0, stream>>>(obs, w1h, w1l, b1, w2h, w2l, b2, out2h, out2l);
  gemm3_k<1, 1><<<160, 256, 0, stream>>>(out2h, out2l, fwh, fwl, fcb, xh, xl,
                                         10240, 256, 2592);
  gemm3_k<0, 0><<<640, 256, 0, stream>>>(xh, xl, iwh, iwl, bsum, pre, nullptr,
                                         10240, 1024, 256);
  lstm_k<<<128, 1024, 0, stream>>>(pre, mask, h0, c0, whhh, hs);
  heads_k<<<2560, 256, 0, stream>>>(hs, vw, vb, lw, lb, acts, out);
}

// Round 9
// 1273.158 us; speedup vs baseline: 1.0396x; 1.0396x over previous
//
#include <hip/hip_runtime.h>

typedef unsigned short u16;
typedef unsigned int   u32;
typedef unsigned long long u64;
typedef short    s8v  __attribute__((ext_vector_type(8)));   // 8 x bf16 bits
typedef float    f4v  __attribute__((ext_vector_type(4)));
typedef u64      ul2v __attribute__((ext_vector_type(2)));
typedef _Float16 h2v  __attribute__((ext_vector_type(2)));

#define DEV __device__ __forceinline__

DEV u16 f2bf(float f) {                       // fp32 -> bf16 (round-half-up)
  u32 u = __builtin_bit_cast(u32, f);
  return (u16)((u + 0x8000u) >> 16);
}
DEV float bf2f(u16 b) { u32 u = ((u32)b) << 16; return __builtin_bit_cast(float, u); }
DEV void splitbf(float f, u16& hi, u16& lo) { // f ~= hi + lo (bf16 pair)
  hi = f2bf(f);
  lo = f2bf(f - bf2f(hi));
}
DEV u16 f2h(float f) {                        // fp32 -> fp16 bits (RNE)
  _Float16 h = (_Float16)f;
  return __builtin_bit_cast(u16, h);
}
DEV float h2f(u16 b) { _Float16 h = __builtin_bit_cast(_Float16, b); return (float)h; }
DEV float fdot2u(u32 a, u32 b, float c) {     // half2 dot + acc (fp32)
#if __has_builtin(__builtin_amdgcn_fdot2)
  return __builtin_amdgcn_fdot2(__builtin_bit_cast(h2v, a),
                                __builtin_bit_cast(h2v, b), c, false);
#else
  h2v x = __builtin_bit_cast(h2v, a), y = __builtin_bit_cast(h2v, b);
  return c + (float)x[0]*(float)y[0] + (float)x[1]*(float)y[1];
#endif
}
DEV float sigm(float x) { return 1.f / (1.f + __expf(-x)); }
DEV f4v mfma16(s8v a, s8v b, f4v c) {
  return __builtin_amdgcn_mfma_f32_16x16x32_bf16(a, b, c, 0, 0, 0);
}
// load 8 contiguous fp32 and split into hi/lo bf16 MFMA fragments
DEV void split8(const float* __restrict__ ap, s8v& Ah, s8v& Al) {
  const float4 v0 = *(const float4*)ap;
  const float4 v1 = *(const float4*)(ap + 4);
  const float f[8] = {v0.x, v0.y, v0.z, v0.w, v1.x, v1.y, v1.z, v1.w};
  uint4 hh, ll;
  u32 hp[4], lp[4];
  #pragma unroll
  for (int i = 0; i < 4; ++i) {
    u16 ha, la, hb, lb;
    splitbf(f[2 * i], ha, la);
    splitbf(f[2 * i + 1], hb, lb);
    hp[i] = (u32)ha | ((u32)hb << 16);
    lp[i] = (u32)la | ((u32)lb << 16);
  }
  hh.x = hp[0]; hh.y = hp[1]; hh.z = hp[2]; hh.w = hp[3];
  ll.x = lp[0]; ll.y = lp[1]; ll.z = lp[2]; ll.w = lp[3];
  Ah = __builtin_bit_cast(s8v, hh);
  Al = __builtin_bit_cast(s8v, ll);
}

// ---------------- prep: split-bf16 weight conversions ----------------
__global__ void prep_k(const float* __restrict__ w1, const float* __restrict__ w2,
                       const float* __restrict__ fcw, const float* __restrict__ wih,
                       const float* __restrict__ whh, const float* __restrict__ bih,
                       const float* __restrict__ bhh,
                       u16* __restrict__ w1h, u16* __restrict__ w1l,
                       u16* __restrict__ w2h, u16* __restrict__ w2l,
                       u16* __restrict__ fh,  u16* __restrict__ fl,
                       u16* __restrict__ ih,  u16* __restrict__ il,
                       u16* __restrict__ whhh, float* __restrict__ bsum) {
  const int i0 = blockIdx.x * 256 + threadIdx.x;
  const int st = gridDim.x * 256;
  for (int i = i0; i < 663552; i += st) splitbf(fcw[i], fh[i], fl[i]);
  for (int i = i0; i < 262144; i += st) splitbf(wih[i], ih[i], il[i]);
  for (int i = i0; i < 262144; i += st) whhh[i] = f2h(whh[i]);
  for (int i = i0; i < 4096;   i += st) splitbf(w1[i], w1h[i], w1l[i]);
  for (int i = i0; i < 8192;   i += st) {
    const int oc = i >> 8, k = i & 255;
    const int ky = k >> 6, kx = (k >> 4) & 3, cc = k & 15;   // k = ky*64+kx*16+c
    splitbf(w2[((oc * 16 + cc) * 4 + ky) * 4 + kx], w2h[i], w2l[i]);
  }
  for (int i = i0; i < 1024; i += st) bsum[i] = bih[i] + bhh[i];
}

// ---------------- conv1: barrier-free, zero LDS, t1 -> global ----------
// Block = one image, 4 waves x 6-7 chunks. A-fragments read directly from
// global obs (8 contiguous aligned fp32/lane; wave = 4 rows x 256 B
// contiguous segments -> full cache lines; 4x k-overlap absorbed by L1/L2)
// and split to hi/lo bf16 in registers. No LDS, no barriers -> occupancy
// bounded only by ~110 VGPRs (R6/R7/R8 lesson: every convs variant coupling
// image-wide LDS staging + barriers to a 4-wave block sat at 12% occupancy,
// latency-bound; paying 524 MB extra HBM (~82us) to decouple buys 3-8x
// more resident waves).
__global__ __launch_bounds__(256) void conv1_k(const float* __restrict__ obs,
    const u16* __restrict__ w1h, const u16* __restrict__ w1l,
    const float* __restrict__ b1,
    u16* __restrict__ t1hg, u16* __restrict__ t1lg, int n0) {
  const int tid = threadIdx.x;
  const int lane = tid & 63;
  const int wid = tid >> 6;
  const int l15 = lane & 15, kc = lane >> 4;
  const int n = blockIdx.x + n0;
  s8v bw1h[8], bw1l[8];                     // conv1 weights resident (64 VGPR)
  #pragma unroll
  for (int k0 = 0; k0 < 8; ++k0) {
    const int o1 = l15 * 256 + k0 * 32 + kc * 8;
    bw1h[k0] = *(const s8v*)(w1h + o1);
    bw1l[k0] = *(const s8v*)(w1l + o1);
  }
  const float bias1 = b1[l15];
  const float* img = obs + (u64)n * 28224;
  u16* dh = t1hg + (u64)blockIdx.x * 6400;  // [400][16] per image
  u16* dl = t1lg + (u64)blockIdx.x * 6400;
  for (int ch = wid; ch < 25; ch += 4) {
    const int p = ch * 16 + l15;
    const int oy = p / 20, ox = p - oy * 20;
    const float* ab = img + oy * 336 + ox * 4;      // (4*oy)*84 + 4*ox
    f4v ahh = {0,0,0,0}, ahl = {0,0,0,0}, alh = {0,0,0,0};
    #pragma unroll
    for (int k0 = 0; k0 < 8; ++k0) {
      const int kb = k0 * 32 + kc * 8;              // k = c*64 + ky*8 + kx
      const int c = kb >> 6, ky = (kb >> 3) & 7;
      s8v Ah, Al;
      split8(ab + c * 7056 + ky * 84, Ah, Al);
      ahh = mfma16(Ah, bw1h[k0], ahh);
      ahl = mfma16(Ah, bw1l[k0], ahl);
      alh = mfma16(Al, bw1h[k0], alh);
    }
    const int pr0 = ch * 16 + (lane >> 4) * 4;
    #pragma unroll
    for (int r = 0; r < 4; ++r) {
      float v = fmaxf(ahh[r] + ahl[r] + alh[r] + bias1, 0.f);
      u16 hi, lo; splitbf(v, hi, lo);
      dh[(pr0 + r) * 16 + l15] = hi;
      dl[(pr0 + r) * 16 + l15] = lo;
    }
  }
}

// ---------------- conv2: stage t1 in LDS (stride-24 pad), 2 barriers ----
// Block = one image; LDS 48.8 KB -> 3 blocks/CU (12 waves). B-fragments
// from global (L1-hot, wave-invariant ot hoists them).
__global__ __launch_bounds__(256) void conv2_k(const u16* __restrict__ t1hg,
    const u16* __restrict__ t1lg,
    const u16* __restrict__ w2h, const u16* __restrict__ w2l,
    const float* __restrict__ b2,
    u16* __restrict__ out2h, u16* __restrict__ out2l, int n0) {
  __shared__ __align__(16) u16 t1h[400 * 24], t1l[400 * 24]; // 38.4 KB
  __shared__ __align__(16) u16 t2h[2592], t2l[2592];         // 10.4 KB
  const int tid = threadIdx.x;
  const int lane = tid & 63;
  const int wid = tid >> 6;
  const int l15 = lane & 15, kc = lane >> 4;
  const int n = blockIdx.x + n0;
  const float bb2a = b2[l15], bb2b = b2[16 + l15];
  // stage t1 [400][16] global -> [400][24] LDS (u32 moves, coalesced)
  {
    const u32* sh = (const u32*)(t1hg + (u64)blockIdx.x * 6400);
    const u32* sl = (const u32*)(t1lg + (u64)blockIdx.x * 6400);
    for (int i = tid; i < 3200; i += 256) {
      const int row = i >> 3, cp = i & 7;
      *(u32*)(t1h + row * 24 + cp * 2) = sh[i];
      *(u32*)(t1l + row * 24 + cp * 2) = sl[i];
    }
  }
  __syncthreads();
  // conv2 (stride 2, 4x4): 6 chunks x 2 oc-tiles (81 positions padded to 96)
  for (int u = wid; u < 12; u += 4) {
    const int ch = u >> 1, ot = u & 1;      // ot fixed per wave
    const int p = ch * 16 + l15;
    const int pc = p < 81 ? p : 80;
    const int oy = pc / 9, ox = pc - oy * 9;
    const int base = (oy * 40 + ox * 2) * 24;
    f4v ahh2 = {0,0,0,0}, ahl2 = {0,0,0,0}, alh2 = {0,0,0,0};
    #pragma unroll
    for (int k0 = 0; k0 < 8; ++k0) {
      const int kb = k0 * 32 + kc * 8;      // k = ky*64 + kx*16 + c
      const int ky = kb >> 6, kx = (kb >> 4) & 3, c0 = kb & 15;
      const int off = base + (ky * 20 + kx) * 24 + c0;
      s8v Ah = *(const s8v*)(t1h + off);
      s8v Al = *(const s8v*)(t1l + off);
      const int wo = (ot * 16 + l15) * 256 + k0 * 32 + kc * 8;
      s8v Bh = *(const s8v*)(w2h + wo);
      s8v Bl = *(const s8v*)(w2l + wo);
      ahh2 = mfma16(Ah, Bh, ahh2);
      ahl2 = mfma16(Ah, Bl, ahl2);
      alh2 = mfma16(Al, Bh, alh2);
    }
    const float bb = ot ? bb2b : bb2a;
    const int oc = ot * 16 + l15;
    const int pr0 = ch * 16 + (lane >> 4) * 4;
    #pragma unroll
    for (int r = 0; r < 4; ++r) {
      const int pp = pr0 + r;
      if (pp < 81) {
        float v = fmaxf(ahh2[r] + ahl2[r] + alh2[r] + bb, 0.f);
        u16 hi, lo; splitbf(v, hi, lo);
        t2h[oc * 81 + pp] = hi;
        t2l[oc * 81 + pp] = lo;
      }
    }
  }
  __syncthreads();
  // t2 -> out2[n][2592] (flat order c*81 + oy*9 + ox, matches fc_w)
  {
    u32* dh = (u32*)(out2h + (u64)n * 2592);
    u32* dl = (u32*)(out2l + (u64)n * 2592);
    const u32* sh = (const u32*)t2h;
    const u32* sl = (const u32*)t2l;
    for (int e = tid; e < 1296; e += 256) { dh[e] = sh[e]; dl[e] = sl[e]; }
  }
}

// ------- split-bf16 GEMM: C = A(MxK) * B(NxK)^T, A~Ah+Al, B~Bh+Bl -------
// BM=BN=128, BK=32, 4 waves (2x2), each wave 64x64 via 4x4 16x16x32 MFMA
template <int RELU, int OSPLIT>
__global__ __launch_bounds__(256) void gemm3_k(const u16* __restrict__ Ah,
    const u16* __restrict__ Al, const u16* __restrict__ Bh, const u16* __restrict__ Bl,
    const float* __restrict__ bias, void* __restrict__ o1, void* __restrict__ o2,
    int M, int N, int K) {
  __shared__ __align__(16) u16 lAh[4096], lAl[4096];  // [128][32]
  __shared__ __align__(16) u16 lBh[4096], lBl[4096];  // [128][32]
  const int tid = threadIdx.x, lane = tid & 63, wid = tid >> 6;
  const int nb = N >> 7;
  const int bm = (int)blockIdx.x / nb, bn = (int)blockIdx.x % nb;
  const int m0 = bm << 7, n0 = bn << 7;
  const int wr = wid >> 1, wc = wid & 1;
  const int l15 = lane & 15, l4 = lane >> 4;
  f4v acc[4][4] = {};
  const int srow = tid >> 2;
  const int scol = (tid & 3) << 3;
  const u64 rA0 = (u64)(m0 + srow) * K + scol;
  const u64 rA1 = (u64)(m0 + 64 + srow) * K + scol;
  const u64 rB0 = (u64)(n0 + srow) * K + scol;
  const u64 rB1 = (u64)(n0 + 64 + srow) * K + scol;
  for (int k0 = 0; k0 < K; k0 += 32) {
    uint4 vah0 = *(const uint4*)(Ah + rA0 + k0);
    uint4 vah1 = *(const uint4*)(Ah + rA1 + k0);
    uint4 val0 = *(const uint4*)(Al + rA0 + k0);
    uint4 val1 = *(const uint4*)(Al + rA1 + k0);
    uint4 vbh0 = *(const uint4*)(Bh + rB0 + k0);
    uint4 vbh1 = *(const uint4*)(Bh + rB1 + k0);
    uint4 vbl0 = *(const uint4*)(Bl + rB0 + k0);
    uint4 vbl1 = *(const uint4*)(Bl + rB1 + k0);
    __syncthreads();
    ((uint4*)lAh)[tid] = vah0;  ((uint4*)lAh)[256 + tid] = vah1;
    ((uint4*)lAl)[tid] = val0;  ((uint4*)lAl)[256 + tid] = val1;
    ((uint4*)lBh)[tid] = vbh0;  ((uint4*)lBh)[256 + tid] = vbh1;
    ((uint4*)lBl)[tid] = vbl0;  ((uint4*)lBl)[256 + tid] = vbl1;
    __syncthreads();
    s8v afh[4], afl[4], bfh[4], bfl[4];
    #pragma unroll
    for (int a = 0; a < 4; ++a) {
      const int off = (wr * 64 + a * 16 + l15) * 32 + l4 * 8;
      afh[a] = *(const s8v*)(lAh + off);
      afl[a] = *(const s8v*)(lAl + off);
    }
    #pragma unroll
    for (int b = 0; b < 4; ++b) {
      const int off = (wc * 64 + b * 16 + l15) * 32 + l4 * 8;
      bfh[b] = *(const s8v*)(lBh + off);
      bfl[b] = *(const s8v*)(lBl + off);
    }
    #pragma unroll
    for (int a = 0; a < 4; ++a)
      #pragma unroll
      for (int b = 0; b < 4; ++b) {
        acc[a][b] = mfma16(afh[a], bfh[b], acc[a][b]);
        acc[a][b] = mfma16(afh[a], bfl[b], acc[a][b]);
        acc[a][b] = mfma16(afl[a], bfh[b], acc[a][b]);
      }
  }
  #pragma unroll
  for (int a = 0; a < 4; ++a) {
    const int mr = m0 + wr * 64 + a * 16 + l4 * 4;
    #pragma unroll
    for (int b = 0; b < 4; ++b) {
      const int col = n0 + wc * 64 + b * 16 + l15;
      const float bv = bias[col];
      #pragma unroll
      for (int r = 0; r < 4; ++r) {
        float v = acc[a][b][r] + bv;
        if (RELU) v = fmaxf(v, 0.f);
        const u64 idx = (u64)(mr + r) * N + col;
        if (OSPLIT) {
          u16 hi, lo; splitbf(v, hi, lo);
          ((u16*)o1)[idx] = hi;
          ((u16*)o2)[idx] = lo;
        } else {
          ((float*)o1)[idx] = v;
        }
      }
    }
  }
}

// ---------------- LSTM scan: 1 workgroup (1024 thr) per batch element ----
// thread (col=t&255, kq=t>>8) owns the K-QUARTER [kq*64, kq*64+64) of gate
// rows col (i), 256+col (f), 512+col (g) in VGPRs: 3 gates x 8 uint4 = 96
// VGPRs of weights — fits the 128-VGPR cap the compiler grants 1024-thread
// blocks (R4/R5 lesson: design to the cap instead of fighting it). o-gate
// rows in LDS chunk-transposed [kp4][col] (measured: 0 bank conflicts).
// h carried as fp16 hi+lo pair (fp32-grade). K-quarter partials reduced
// via 12 KB LDS. kq is wave-uniform -> divergence-free.
__global__ __launch_bounds__(1024) void lstm_k(const float* __restrict__ pre,
    const float* __restrict__ mask, const float* __restrict__ h0,
    const float* __restrict__ c0, const u16* __restrict__ whh,
    float* __restrict__ hs) {
  __shared__ __align__(16) uint4 lds_o[32 * 256];   // [kp4][col], 128 KB
  __shared__ __align__(16) float4 lds_red[3 * 256]; // kq=1..3 partials, 12 KB
  __shared__ __align__(16) u32 lds_hh[128];         // h hi (fp16 pairs)
  __shared__ __align__(16) u32 lds_hl[128];         // h lo
  const int t = threadIdx.x, b = blockIdx.x;
  const int col = t & 255, kq = t >> 8;             // kq wave-uniform
  // gate-row weights, K-quarter each: 8 uint4 per gate = 96 VGPRs total
  uint4 wi[8], wf[8], wg[8];
  {
    const u32* wb = (const u32*)whh;
    const uint4* pi_ = (const uint4*)(wb + (u64)col * 128) + kq * 8;
    const uint4* pf_ = (const uint4*)(wb + (u64)(256 + col) * 128) + kq * 8;
    const uint4* pg_ = (const uint4*)(wb + (u64)(512 + col) * 128) + kq * 8;
    #pragma unroll
    for (int q = 0; q < 8; ++q) {
      wi[q] = pi_[q]; wf[q] = pf_[q]; wg[q] = pg_[q];
    }
    // o-gate row quarter -> LDS chunk-transposed
    const uint4* po_ = (const uint4*)(wb + (u64)(768 + col) * 128);
    #pragma unroll
    for (int j = 0; j < 8; ++j) {
      const int kp4 = kq * 8 + j;
      lds_o[kp4 * 256 + col] = po_[kp4];
    }
  }
  float c = 0.f;
  if (kq == 0) c = c0[b * 256 + col];
  if (t < 128) {
    float a0 = h0[b * 256 + 2 * t], a1 = h0[b * 256 + 2 * t + 1];
    u16 h0a = f2h(a0); u16 l0a = f2h(a0 - h2f(h0a));
    u16 h1a = f2h(a1); u16 l1a = f2h(a1 - h2f(h1a));
    lds_hh[t] = (u32)h0a | ((u32)h1a << 16);
    lds_hl[t] = (u32)l0a | ((u32)l1a << 16);
  }
  float npi = 0.f, npf = 0.f, npg = 0.f, npo = 0.f;
  if (kq == 0) {                                    // prefetch step-0 pre
    const float* pr = pre + (u64)b * 1024;
    npi = pr[col]; npf = pr[256 + col]; npg = pr[512 + col]; npo = pr[768 + col];
  }
  __syncthreads();
  for (int s = 0; s < 80; ++s) {
    float ai = npi, afv = npf, ag = npg, ao = npo;  // kq!=0: zeros (partials)
    #pragma unroll
    for (int j = 0; j < 8; ++j) {
      const int kk = kq * 8 + j;
      const uint4 ov = lds_o[kk * 256 + col];       // conflict-free
      const uint4 hh = ((const uint4*)lds_hh)[kk];  // broadcast
      const uint4 hl = ((const uint4*)lds_hl)[kk];  // broadcast
      ai  = fdot2u(wi[j].x, hh.x, ai);  ai  = fdot2u(wi[j].y, hh.y, ai);
      ai  = fdot2u(wi[j].z, hh.z, ai);  ai  = fdot2u(wi[j].w, hh.w, ai);
      ai  = fdot2u(wi[j].x, hl.x, ai);  ai  = fdot2u(wi[j].y, hl.y, ai);
      ai  = fdot2u(wi[j].z, hl.z, ai);  ai  = fdot2u(wi[j].w, hl.w, ai);
      afv = fdot2u(wf[j].x, hh.x, afv); afv = fdot2u(wf[j].y, hh.y, afv);
      afv = fdot2u(wf[j].z, hh.z, afv); afv = fdot2u(wf[j].w, hh.w, afv);
      afv = fdot2u(wf[j].x, hl.x, afv); afv = fdot2u(wf[j].y, hl.y, afv);
      afv = fdot2u(wf[j].z, hl.z, afv); afv = fdot2u(wf[j].w, hl.w, afv);
      ag  = fdot2u(wg[j].x, hh.x, ag);  ag  = fdot2u(wg[j].y, hh.y, ag);
      ag  = fdot2u(wg[j].z, hh.z, ag);  ag  = fdot2u(wg[j].w, hh.w, ag);
      ag  = fdot2u(wg[j].x, hl.x, ag);  ag  = fdot2u(wg[j].y, hl.y, ag);
      ag  = fdot2u(wg[j].z, hl.z, ag);  ag  = fdot2u(wg[j].w, hl.w, ag);
      ao  = fdot2u(ov.x, hh.x, ao);     ao  = fdot2u(ov.y, hh.y, ao);
      ao  = fdot2u(ov.z, hh.z, ao);     ao  = fdot2u(ov.w, hh.w, ao);
      ao  = fdot2u(ov.x, hl.x, ao);     ao  = fdot2u(ov.y, hl.y, ao);
      ao  = fdot2u(ov.z, hl.z, ao);     ao  = fdot2u(ov.w, hl.w, ao);
    }
    if (kq != 0) {
      float4 r; r.x = ai; r.y = afv; r.z = ag; r.w = ao;
      lds_red[(kq - 1) * 256 + col] = r;
    } else if (s + 1 < 80) {                        // prefetch next-step pre
      const float* pr = pre + (u64)((s + 1) * 128 + b) * 1024;
      npi = pr[col]; npf = pr[256 + col]; npg = pr[512 + col]; npo = pr[768 + col];
    }
    __syncthreads();
    if (kq == 0) {
      const float4 r1 = lds_red[col];
      const float4 r2 = lds_red[256 + col];
      const float4 r3 = lds_red[512 + col];
      ai += r1.x + r2.x + r3.x;
      afv += r1.y + r2.y + r3.y;
      ag += r1.z + r2.z + r3.z;
      ao += r1.w + r2.w + r3.w;
      const float m = mask[s * 128 + b];
      const float ig = sigm(ai), fg = sigm(afv), og = sigm(ao);
      const float gg = tanhf(ag);
      const float cn = fg * c + ig * gg;
      const float hn = og * tanhf(cn);
      hs[(u64)(s * 128 + b) * 256 + col] = hn;      // unmasked output
      c = cn * m;
      const float hm = hn * m;                      // masked carry
      u16 hhi = f2h(hm);
      u16 hlo = f2h(hm - h2f(hhi));
      ((u16*)lds_hh)[col] = hhi;
      ((u16*)lds_hl)[col] = hlo;
    }
    __syncthreads();
  }
}

// ---------------- heads: value, log-softmax, entropy, action gather -------
__global__ __launch_bounds__(256) void heads_k(const float* __restrict__ hs,
    const float* __restrict__ vw, const float* __restrict__ vb,
    const float* __restrict__ lw, const float* __restrict__ lb,
    const int* __restrict__ acts, float* __restrict__ out) {
  const int lane = threadIdx.x & 63, wid = threadIdx.x >> 6;
  const int row = blockIdx.x * 4 + wid;
  const float4 h4 = *(const float4*)(hs + (u64)row * 256 + lane * 4);
  float lj[18];
  #pragma unroll
  for (int j = 0; j < 18; ++j) {
    const float4 w4 = *(const float4*)(lw + j * 256 + lane * 4);
    float p = h4.x * w4.x + h4.y * w4.y + h4.z * w4.z + h4.w * w4.w;
    #pragma unroll
    for (int o = 32; o > 0; o >>= 1) p += __shfl_xor(p, o, 64);
    lj[j] = p + lb[j];
  }
  const float4 v4 = *(const float4*)(vw + lane * 4);
  float val = h4.x * v4.x + h4.y * v4.y + h4.z * v4.z + h4.w * v4.w;
  #pragma unroll
  for (int o = 32; o > 0; o >>= 1) val += __shfl_xor(val, o, 64);
  val += vb[0];
  float mx = lj[0];
  #pragma unroll
  for (int j = 1; j < 18; ++j) mx = fmaxf(mx, lj[j]);
  float sum = 0.f;
  #pragma unroll
  for (int j = 0; j < 18; ++j) sum += __expf(lj[j] - mx);
  const float ls = __logf(sum);
  const int a = acts[row];
  float tlp = 0.f, ent = 0.f;
  #pragma unroll
  for (int j = 0; j < 18; ++j) {
    const float lp = lj[j] - mx - ls;
    const float pj = __expf(lp);
    ent -= pj * lp;
    if (j == a) tlp = lp;
  }
  if (lane == 0) {
    out[row]         = tlp;
    out[10240 + row] = ent;
    out[20480 + row] = val;
  }
}

// ---------------- launch ----------------
extern "C" void kernel_launch(void* const* d_in, const int* in_sizes, int n_in,
                              void* d_out, int out_size, void* d_ws, size_t ws_size,
                              hipStream_t stream) {
  const float* obs  = (const float*)d_in[0];
  const float* mask = (const float*)d_in[1];
  const float* h0   = (const float*)d_in[2];
  const float* c0   = (const float*)d_in[3];
  const int*   acts = (const int*)d_in[4];
  const float* w1   = (const float*)d_in[5];
  const float* b1   = (const float*)d_in[6];
  const float* w2   = (const float*)d_in[7];
  const float* b2   = (const float*)d_in[8];
  const float* fcw  = (const float*)d_in[9];
  const float* fcb  = (const float*)d_in[10];
  const float* wih  = (const float*)d_in[11];
  const float* whh  = (const float*)d_in[12];
  const float* bih  = (const float*)d_in[13];
  const float* bhh  = (const float*)d_in[14];
  const float* vw   = (const float*)d_in[15];
  const float* vb   = (const float*)d_in[16];
  const float* lw   = (const float*)d_in[17];
  const float* lb   = (const float*)d_in[18];
  float* out = (float*)d_out;

  char* cur = (char*)d_ws;
  auto carve = [&](size_t bytes) {
    void* p = cur; cur += (bytes + 255) & ~(size_t)255; return p;
  };
  u16*   out2h = (u16*)carve(10240ULL * 2592 * 2);
  u16*   out2l = (u16*)carve(10240ULL * 2592 * 2);
  u16*   xh    = (u16*)carve(10240ULL * 256 * 2);
  u16*   xl    = (u16*)carve(10240ULL * 256 * 2);
  float* pre   = (float*)carve(10240ULL * 1024 * 4);
  float* hs    = (float*)carve(10240ULL * 256 * 4);
  u16*   t1hg  = (u16*)carve(5120ULL * 6400 * 2);   // conv1 out, half batch
  u16*   t1lg  = (u16*)carve(5120ULL * 6400 * 2);
  u16*   w1h   = (u16*)carve(4096ULL * 2);
  u16*   w1l   = (u16*)carve(4096ULL * 2);
  u16*   w2h   = (u16*)carve(8192ULL * 2);
  u16*   w2l   = (u16*)carve(8192ULL * 2);
  u16*   fwh   = (u16*)carve(663552ULL * 2);
  u16*   fwl   = (u16*)carve(663552ULL * 2);
  u16*   iwh   = (u16*)carve(262144ULL * 2);
  u16*   iwl   = (u16*)carve(262144ULL * 2);
  u16*   whhh  = (u16*)carve(262144ULL * 2);
  float* bsum  = (float*)carve(1024ULL * 4);

  prep_k<<<512, 256, 0, stream>>>(w1, w2, fcw, wih, whh, bih, bhh,
                                  w1h, w1l, w2h, w2l, fwh, fwl, iwh, iwl, whhh, bsum);
  // two passes over the batch, reusing the 131 MB t1 buffer
  conv1_k<<<5120, 256, 0, stream>>>(obs, w1h, w1l, b1, t1hg, t1lg, 0);
  conv2_k<<<5120, 256, 0, stream>>>(t1hg, t1lg, w2h, w2l, b2, out2h, out2l, 0);
  conv1_k<<<5120, 256, 0, stream>>>(obs, w1h, w1l, b1, t1hg, t1lg, 5120);
  conv2_k<<<5120, 256, 0, stream>>>(t1hg, t1lg, w2h, w2l, b2, out2h, out2l, 5120);
  gemm3_k<1, 1><<<160, 256, 0, stream>>>(out2h, out2l, fwh, fwl, fcb, xh, xl,
                                         10240, 256, 2592);
  gemm3_k<0, 0><<<640, 256, 0, stream>>>(xh, xl, iwh, iwl, bsum, pre, nullptr,
                                         10240, 1024, 256);
  lstm_k<<<128, 1024, 0, stream>>>(pre, mask, h0, c0, whhh, hs);
  heads_k<<<2560, 256, 0, stream>>>(hs, vw, vb, lw, lb, acts, out);
}

// Round 10
// 1119.659 us; speedup vs baseline: 1.1822x; 1.1371x over previous
//
#include <hip/hip_runtime.h>

typedef unsigned short u16;
typedef unsigned int   u32;
typedef unsigned long long u64;
typedef short    s8v  __attribute__((ext_vector_type(8)));   // 8 x bf16 bits
typedef float    f4v  __attribute__((ext_vector_type(4)));
typedef u64      ul2v __attribute__((ext_vector_type(2)));
typedef _Float16 h2v  __attribute__((ext_vector_type(2)));

#define DEV __device__ __forceinline__

DEV u16 f2bf(float f) {                       // fp32 -> bf16 (round-half-up)
  u32 u = __builtin_bit_cast(u32, f);
  return (u16)((u + 0x8000u) >> 16);
}
DEV float bf2f(u16 b) { u32 u = ((u32)b) << 16; return __builtin_bit_cast(float, u); }
DEV void splitbf(float f, u16& hi, u16& lo) { // f ~= hi + lo (bf16 pair)
  hi = f2bf(f);
  lo = f2bf(f - bf2f(hi));
}
DEV u16 f2h(float f) {                        // fp32 -> fp16 bits (RNE)
  _Float16 h = (_Float16)f;
  return __builtin_bit_cast(u16, h);
}
DEV float h2f(u16 b) { _Float16 h = __builtin_bit_cast(_Float16, b); return (float)h; }
DEV float fdot2u(u32 a, u32 b, float c) {     // half2 dot + acc (fp32)
#if __has_builtin(__builtin_amdgcn_fdot2)
  return __builtin_amdgcn_fdot2(__builtin_bit_cast(h2v, a),
                                __builtin_bit_cast(h2v, b), c, false);
#else
  h2v x = __builtin_bit_cast(h2v, a), y = __builtin_bit_cast(h2v, b);
  return c + (float)x[0]*(float)y[0] + (float)x[1]*(float)y[1];
#endif
}
DEV float sigm(float x) { return 1.f / (1.f + __expf(-x)); }
DEV f4v mfma16(s8v a, s8v b, f4v c) {
  return __builtin_amdgcn_mfma_f32_16x16x32_bf16(a, b, c, 0, 0, 0);
}
// load 8 contiguous fp32 and split into hi/lo bf16 MFMA fragments
DEV void split8(const float* __restrict__ ap, s8v& Ah, s8v& Al) {
  const float4 v0 = *(const float4*)ap;
  const float4 v1 = *(const float4*)(ap + 4);
  const float f[8] = {v0.x, v0.y, v0.z, v0.w, v1.x, v1.y, v1.z, v1.w};
  uint4 hh, ll;
  u32 hp[4], lp[4];
  #pragma unroll
  for (int i = 0; i < 4; ++i) {
    u16 ha, la, hb, lb;
    splitbf(f[2 * i], ha, la);
    splitbf(f[2 * i + 1], hb, lb);
    hp[i] = (u32)ha | ((u32)hb << 16);
    lp[i] = (u32)la | ((u32)lb << 16);
  }
  hh.x = hp[0]; hh.y = hp[1]; hh.z = hp[2]; hh.w = hp[3];
  ll.x = lp[0]; ll.y = lp[1]; ll.z = lp[2]; ll.w = lp[3];
  Ah = __builtin_bit_cast(s8v, hh);
  Al = __builtin_bit_cast(s8v, ll);
}

// ---------------- prep: split-bf16 weight conversions ----------------
__global__ void prep_k(const float* __restrict__ w1, const float* __restrict__ w2,
                       const float* __restrict__ fcw, const float* __restrict__ wih,
                       const float* __restrict__ whh, const float* __restrict__ bih,
                       const float* __restrict__ bhh,
                       u16* __restrict__ w1h, u16* __restrict__ w1l,
                       u16* __restrict__ w2h, u16* __restrict__ w2l,
                       u16* __restrict__ fh,  u16* __restrict__ fl,
                       u16* __restrict__ ih,  u16* __restrict__ il,
                       u16* __restrict__ whhh, float* __restrict__ bsum) {
  const int i0 = blockIdx.x * 256 + threadIdx.x;
  const int st = gridDim.x * 256;
  for (int i = i0; i < 663552; i += st) splitbf(fcw[i], fh[i], fl[i]);
  for (int i = i0; i < 262144; i += st) splitbf(wih[i], ih[i], il[i]);
  for (int i = i0; i < 262144; i += st) whhh[i] = f2h(whh[i]);
  for (int i = i0; i < 4096;   i += st) splitbf(w1[i], w1h[i], w1l[i]);
  for (int i = i0; i < 8192;   i += st) {
    const int oc = i >> 8, k = i & 255;
    const int ky = k >> 6, kx = (k >> 4) & 3, cc = k & 15;   // k = ky*64+kx*16+c
    splitbf(w2[((oc * 16 + cc) * 4 + ky) * 4 + kx], w2h[i], w2l[i]);
  }
  for (int i = i0; i < 1024; i += st) bsum[i] = bih[i] + bhh[i];
}

// -------- fused conv1+conv2, wave-private strips, ZERO barriers --------
// Wave W = blockIdx*4+wid handles strip s=W%3 of image n=W/3: conv2 output
// rows 3s..3s+2 (27 pos x 32 oc) <- t1 rows 6s..6s+7 (160 pos, 20% seam
// recompute). The wave computes conv1 for its own patch into a PRIVATE LDS
// slice and immediately consumes it for conv2 — same-wave producer/consumer
// means no __syncthreads at all (compiler lgkmcnt suffices). R6-R9 lesson:
// every structure coupling waves via barriers around image-wide LDS sat at
// ~12% occupancy / 660-940us; this removes every wait except memory itself.
// obs A-fragments read direct from global (R7 pattern: 8 contiguous aligned
// fp32/lane, 4x window overlap served by L1/L2). LDS 41 KB -> 3 blocks/CU.
// conv2 LDS reads are 8-way conflicted (stride-16; fragment granularity
// admits no useful swizzle) — costed ~25us chip-wide, accepted.
__global__ __launch_bounds__(256) void conv_k(const float* __restrict__ obs,
    const u16* __restrict__ w1h, const u16* __restrict__ w1l, const float* __restrict__ b1,
    const u16* __restrict__ w2h, const u16* __restrict__ w2l, const float* __restrict__ b2,
    u16* __restrict__ out2h, u16* __restrict__ out2l) {
  __shared__ __align__(16) u16 t1h[4][2560], t1l[4][2560]; // [wave][160pos][16oc]
  const int tid = threadIdx.x, lane = tid & 63, wid = tid >> 6;
  const int l15 = lane & 15, kc = lane >> 4;
  const int W = blockIdx.x * 4 + wid;
  const int n = W / 3, s = W - n * 3;            // image, strip
  u16* th = t1h[wid];
  u16* tl = t1l[wid];
  s8v bw1h[8], bw1l[8];                          // conv1 weights (64 VGPR)
  #pragma unroll
  for (int k0 = 0; k0 < 8; ++k0) {
    const int o1 = l15 * 256 + k0 * 32 + kc * 8;
    bw1h[k0] = *(const s8v*)(w1h + o1);
    bw1l[k0] = *(const s8v*)(w1l + o1);
  }
  const float bias1 = b1[l15];
  const float* img = obs + (u64)n * 28224 + s * 2016;  // + (6s rows)*336
  // conv1 over the strip: 160 positions = 10 chunks of 16
  for (int ch = 0; ch < 10; ++ch) {
    const int p = ch * 16 + l15;
    const int ty = p / 20, tx = p - ty * 20;
    const float* ab = img + ty * 336 + tx * 4;   // (4*ty)*84 + 4*tx
    f4v ahh = {0,0,0,0}, ahl = {0,0,0,0}, alh = {0,0,0,0};
    #pragma unroll
    for (int k0 = 0; k0 < 8; ++k0) {
      const int kb = k0 * 32 + kc * 8;           // k = c*64 + ky*8 + kx
      const int c = kb >> 6, ky = (kb >> 3) & 7;
      s8v Ah, Al;
      split8(ab + c * 7056 + ky * 84, Ah, Al);
      ahh = mfma16(Ah, bw1h[k0], ahh);
      ahl = mfma16(Ah, bw1l[k0], ahl);
      alh = mfma16(Al, bw1h[k0], alh);
    }
    const int pr0 = ch * 16 + kc * 4;
    #pragma unroll
    for (int r = 0; r < 4; ++r) {
      const int pos = pr0 + r;
      float v = fmaxf(ahh[r] + ahl[r] + alh[r] + bias1, 0.f);
      u16 hi, lo; splitbf(v, hi, lo);
      th[pos * 16 + l15] = hi;
      tl[pos * 16 + l15] = lo;
    }
  }
  // conv2 (same wave reads its own t1 slice — no barrier)
  const float bb2a = b2[l15], bb2b = b2[16 + l15];
  #pragma unroll
  for (int g = 0; g < 4; ++g) {
    const int ch = g >> 1, ot = g & 1;
    const int p = ch * 16 + l15;                 // local conv2 pos (27 valid)
    const int pc = p < 27 ? p : 26;
    const int ly = pc / 9, lx = pc - ly * 9;
    f4v a0 = {0,0,0,0}, a1 = {0,0,0,0}, a2 = {0,0,0,0};
    #pragma unroll
    for (int k0 = 0; k0 < 8; ++k0) {
      const int kb = k0 * 32 + kc * 8;           // k = ky*64 + kx*16 + c
      const int ky = kb >> 6, kx = (kb >> 4) & 3, c0 = kb & 15;
      const int pos = ly * 40 + lx * 2 + ky * 20 + kx;
      s8v Ah = *(const s8v*)(th + pos * 16 + c0);
      s8v Al = *(const s8v*)(tl + pos * 16 + c0);
      const int wo = (ot * 16 + l15) * 256 + k0 * 32 + kc * 8;
      s8v Bh = *(const s8v*)(w2h + wo);
      s8v Bl = *(const s8v*)(w2l + wo);
      a0 = mfma16(Ah, Bh, a0);
      a1 = mfma16(Ah, Bl, a1);
      a2 = mfma16(Al, Bh, a2);
    }
    const float bb = ot ? bb2b : bb2a;
    const int oc = ot * 16 + l15;
    u16* dh = out2h + (u64)n * 2592 + oc * 81 + s * 27;
    u16* dl = out2l + (u64)n * 2592 + oc * 81 + s * 27;
    const int pr0 = ch * 16 + kc * 4;
    #pragma unroll
    for (int r = 0; r < 4; ++r) {
      const int pp = pr0 + r;
      if (pp < 27) {
        float v = fmaxf(a0[r] + a1[r] + a2[r] + bb, 0.f);
        u16 hi, lo; splitbf(v, hi, lo);
        dh[pp] = hi;
        dl[pp] = lo;
      }
    }
  }
}

// ------- split-bf16 GEMM: C = A(MxK) * B(NxK)^T, A~Ah+Al, B~Bh+Bl -------
// BM=BN=128, BK=32, 4 waves (2x2), each wave 64x64 via 4x4 16x16x32 MFMA
template <int RELU, int OSPLIT>
__global__ __launch_bounds__(256) void gemm3_k(const u16* __restrict__ Ah,
    const u16* __restrict__ Al, const u16* __restrict__ Bh, const u16* __restrict__ Bl,
    const float* __restrict__ bias, void* __restrict__ o1, void* __restrict__ o2,
    int M, int N, int K) {
  __shared__ __align__(16) u16 lAh[4096], lAl[4096];  // [128][32]
  __shared__ __align__(16) u16 lBh[4096], lBl[4096];  // [128][32]
  const int tid = threadIdx.x, lane = tid & 63, wid = tid >> 6;
  const int nb = N >> 7;
  const int bm = (int)blockIdx.x / nb, bn = (int)blockIdx.x % nb;
  const int m0 = bm << 7, n0 = bn << 7;
  const int wr = wid >> 1, wc = wid & 1;
  const int l15 = lane & 15, l4 = lane >> 4;
  f4v acc[4][4] = {};
  const int srow = tid >> 2;
  const int scol = (tid & 3) << 3;
  const u64 rA0 = (u64)(m0 + srow) * K + scol;
  const u64 rA1 = (u64)(m0 + 64 + srow) * K + scol;
  const u64 rB0 = (u64)(n0 + srow) * K + scol;
  const u64 rB1 = (u64)(n0 + 64 + srow) * K + scol;
  for (int k0 = 0; k0 < K; k0 += 32) {
    uint4 vah0 = *(const uint4*)(Ah + rA0 + k0);
    uint4 vah1 = *(const uint4*)(Ah + rA1 + k0);
    uint4 val0 = *(const uint4*)(Al + rA0 + k0);
    uint4 val1 = *(const uint4*)(Al + rA1 + k0);
    uint4 vbh0 = *(const uint4*)(Bh + rB0 + k0);
    uint4 vbh1 = *(const uint4*)(Bh + rB1 + k0);
    uint4 vbl0 = *(const uint4*)(Bl + rB0 + k0);
    uint4 vbl1 = *(const uint4*)(Bl + rB1 + k0);
    __syncthreads();
    ((uint4*)lAh)[tid] = vah0;  ((uint4*)lAh)[256 + tid] = vah1;
    ((uint4*)lAl)[tid] = val0;  ((uint4*)lAl)[256 + tid] = val1;
    ((uint4*)lBh)[tid] = vbh0;  ((uint4*)lBh)[256 + tid] = vbh1;
    ((uint4*)lBl)[tid] = vbl0;  ((uint4*)lBl)[256 + tid] = vbl1;
    __syncthreads();
    s8v afh[4], afl[4], bfh[4], bfl[4];
    #pragma unroll
    for (int a = 0; a < 4; ++a) {
      const int off = (wr * 64 + a * 16 + l15) * 32 + l4 * 8;
      afh[a] = *(const s8v*)(lAh + off);
      afl[a] = *(const s8v*)(lAl + off);
    }
    #pragma unroll
    for (int b = 0; b < 4; ++b) {
      const int off = (wc * 64 + b * 16 + l15) * 32 + l4 * 8;
      bfh[b] = *(const s8v*)(lBh + off);
      bfl[b] = *(const s8v*)(lBl + off);
    }
    #pragma unroll
    for (int a = 0; a < 4; ++a)
      #pragma unroll
      for (int b = 0; b < 4; ++b) {
        acc[a][b] = mfma16(afh[a], bfh[b], acc[a][b]);
        acc[a][b] = mfma16(afh[a], bfl[b], acc[a][b]);
        acc[a][b] = mfma16(afl[a], bfh[b], acc[a][b]);
      }
  }
  #pragma unroll
  for (int a = 0; a < 4; ++a) {
    const int mr = m0 + wr * 64 + a * 16 + l4 * 4;
    #pragma unroll
    for (int b = 0; b < 4; ++b) {
      const int col = n0 + wc * 64 + b * 16 + l15;
      const float bv = bias[col];
      #pragma unroll
      for (int r = 0; r < 4; ++r) {
        float v = acc[a][b][r] + bv;
        if (RELU) v = fmaxf(v, 0.f);
        const u64 idx = (u64)(mr + r) * N + col;
        if (OSPLIT) {
          u16 hi, lo; splitbf(v, hi, lo);
          ((u16*)o1)[idx] = hi;
          ((u16*)o2)[idx] = lo;
        } else {
          ((float*)o1)[idx] = v;
        }
      }
    }
  }
}

// ---------------- LSTM scan: 1 workgroup (1024 thr) per batch element ----
// thread (col=t&255, kq=t>>8) owns the K-QUARTER [kq*64, kq*64+64) of gate
// rows col (i), 256+col (f), 512+col (g) in VGPRs: 3 gates x 8 uint4 = 96
// VGPRs of weights — fits the 128-VGPR cap the compiler grants 1024-thread
// blocks (R4/R5 lesson: design to the cap instead of fighting it). o-gate
// rows in LDS chunk-transposed [kp4][col] (measured: 0 bank conflicts).
// h carried as fp16 hi+lo pair (fp32-grade). K-quarter partials reduced
// via 12 KB LDS. kq is wave-uniform -> divergence-free.
__global__ __launch_bounds__(1024) void lstm_k(const float* __restrict__ pre,
    const float* __restrict__ mask, const float* __restrict__ h0,
    const float* __restrict__ c0, const u16* __restrict__ whh,
    float* __restrict__ hs) {
  __shared__ __align__(16) uint4 lds_o[32 * 256];   // [kp4][col], 128 KB
  __shared__ __align__(16) float4 lds_red[3 * 256]; // kq=1..3 partials, 12 KB
  __shared__ __align__(16) u32 lds_hh[128];         // h hi (fp16 pairs)
  __shared__ __align__(16) u32 lds_hl[128];         // h lo
  const int t = threadIdx.x, b = blockIdx.x;
  const int col = t & 255, kq = t >> 8;             // kq wave-uniform
  // gate-row weights, K-quarter each: 8 uint4 per gate = 96 VGPRs total
  uint4 wi[8], wf[8], wg[8];
  {
    const u32* wb = (const u32*)whh;
    const uint4* pi_ = (const uint4*)(wb + (u64)col * 128) + kq * 8;
    const uint4* pf_ = (const uint4*)(wb + (u64)(256 + col) * 128) + kq * 8;
    const uint4* pg_ = (const uint4*)(wb + (u64)(512 + col) * 128) + kq * 8;
    #pragma unroll
    for (int q = 0; q < 8; ++q) {
      wi[q] = pi_[q]; wf[q] = pf_[q]; wg[q] = pg_[q];
    }
    // o-gate row quarter -> LDS chunk-transposed
    const uint4* po_ = (const uint4*)(wb + (u64)(768 + col) * 128);
    #pragma unroll
    for (int j = 0; j < 8; ++j) {
      const int kp4 = kq * 8 + j;
      lds_o[kp4 * 256 + col] = po_[kp4];
    }
  }
  float c = 0.f;
  if (kq == 0) c = c0[b * 256 + col];
  if (t < 128) {
    float a0 = h0[b * 256 + 2 * t], a1 = h0[b * 256 + 2 * t + 1];
    u16 h0a = f2h(a0); u16 l0a = f2h(a0 - h2f(h0a));
    u16 h1a = f2h(a1); u16 l1a = f2h(a1 - h2f(h1a));
    lds_hh[t] = (u32)h0a | ((u32)h1a << 16);
    lds_hl[t] = (u32)l0a | ((u32)l1a << 16);
  }
  float npi = 0.f, npf = 0.f, npg = 0.f, npo = 0.f;
  if (kq == 0) {                                    // prefetch step-0 pre
    const float* pr = pre + (u64)b * 1024;
    npi = pr[col]; npf = pr[256 + col]; npg = pr[512 + col]; npo = pr[768 + col];
  }
  __syncthreads();
  for (int s = 0; s < 80; ++s) {
    float ai = npi, afv = npf, ag = npg, ao = npo;  // kq!=0: zeros (partials)
    #pragma unroll
    for (int j = 0; j < 8; ++j) {
      const int kk = kq * 8 + j;
      const uint4 ov = lds_o[kk * 256 + col];       // conflict-free
      const uint4 hh = ((const uint4*)lds_hh)[kk];  // broadcast
      const uint4 hl = ((const uint4*)lds_hl)[kk];  // broadcast
      ai  = fdot2u(wi[j].x, hh.x, ai);  ai  = fdot2u(wi[j].y, hh.y, ai);
      ai  = fdot2u(wi[j].z, hh.z, ai);  ai  = fdot2u(wi[j].w, hh.w, ai);
      ai  = fdot2u(wi[j].x, hl.x, ai);  ai  = fdot2u(wi[j].y, hl.y, ai);
      ai  = fdot2u(wi[j].z, hl.z, ai);  ai  = fdot2u(wi[j].w, hl.w, ai);
      afv = fdot2u(wf[j].x, hh.x, afv); afv = fdot2u(wf[j].y, hh.y, afv);
      afv = fdot2u(wf[j].z, hh.z, afv); afv = fdot2u(wf[j].w, hh.w, afv);
      afv = fdot2u(wf[j].x, hl.x, afv); afv = fdot2u(wf[j].y, hl.y, afv);
      afv = fdot2u(wf[j].z, hl.z, afv); afv = fdot2u(wf[j].w, hl.w, afv);
      ag  = fdot2u(wg[j].x, hh.x, ag);  ag  = fdot2u(wg[j].y, hh.y, ag);
      ag  = fdot2u(wg[j].z, hh.z, ag);  ag  = fdot2u(wg[j].w, hh.w, ag);
      ag  = fdot2u(wg[j].x, hl.x, ag);  ag  = fdot2u(wg[j].y, hl.y, ag);
      ag  = fdot2u(wg[j].z, hl.z, ag);  ag  = fdot2u(wg[j].w, hl.w, ag);
      ao  = fdot2u(ov.x, hh.x, ao);     ao  = fdot2u(ov.y, hh.y, ao);
      ao  = fdot2u(ov.z, hh.z, ao);     ao  = fdot2u(ov.w, hh.w, ao);
      ao  = fdot2u(ov.x, hl.x, ao);     ao  = fdot2u(ov.y, hl.y, ao);
      ao  = fdot2u(ov.z, hl.z, ao);     ao  = fdot2u(ov.w, hl.w, ao);
    }
    if (kq != 0) {
      float4 r; r.x = ai; r.y = afv; r.z = ag; r.w = ao;
      lds_red[(kq - 1) * 256 + col] = r;
    } else if (s + 1 < 80) {                        // prefetch next-step pre
      const float* pr = pre + (u64)((s + 1) * 128 + b) * 1024;
      npi = pr[col]; npf = pr[256 + col]; npg = pr[512 + col]; npo = pr[768 + col];
    }
    __syncthreads();
    if (kq == 0) {
      const float4 r1 = lds_red[col];
      const float4 r2 = lds_red[256 + col];
      const float4 r3 = lds_red[512 + col];
      ai += r1.x + r2.x + r3.x;
      afv += r1.y + r2.y + r3.y;
      ag += r1.z + r2.z + r3.z;
      ao += r1.w + r2.w + r3.w;
      const float m = mask[s * 128 + b];
      const float ig = sigm(ai), fg = sigm(afv), og = sigm(ao);
      const float gg = tanhf(ag);
      const float cn = fg * c + ig * gg;
      const float hn = og * tanhf(cn);
      hs[(u64)(s * 128 + b) * 256 + col] = hn;      // unmasked output
      c = cn * m;
      const float hm = hn * m;                      // masked carry
      u16 hhi = f2h(hm);
      u16 hlo = f2h(hm - h2f(hhi));
      ((u16*)lds_hh)[col] = hhi;
      ((u16*)lds_hl)[col] = hlo;
    }
    __syncthreads();
  }
}

// ---------------- heads: value, log-softmax, entropy, action gather -------
__global__ __launch_bounds__(256) void heads_k(const float* __restrict__ hs,
    const float* __restrict__ vw, const float* __restrict__ vb,
    const float* __restrict__ lw, const float* __restrict__ lb,
    const int* __restrict__ acts, float* __restrict__ out) {
  const int lane = threadIdx.x & 63, wid = threadIdx.x >> 6;
  const int row = blockIdx.x * 4 + wid;
  const float4 h4 = *(const float4*)(hs + (u64)row * 256 + lane * 4);
  float lj[18];
  #pragma unroll
  for (int j = 0; j < 18; ++j) {
    const float4 w4 = *(const float4*)(lw + j * 256 + lane * 4);
    float p = h4.x * w4.x + h4.y * w4.y + h4.z * w4.z + h4.w * w4.w;
    #pragma unroll
    for (int o = 32; o > 0; o >>= 1) p += __shfl_xor(p, o, 64);
    lj[j] = p + lb[j];
  }
  const float4 v4 = *(const float4*)(vw + lane * 4);
  float val = h4.x * v4.x + h4.y * v4.y + h4.z * v4.z + h4.w * v4.w;
  #pragma unroll
  for (int o = 32; o > 0; o >>= 1) val += __shfl_xor(val, o, 64);
  val += vb[0];
  float mx = lj[0];
  #pragma unroll
  for (int j = 1; j < 18; ++j) mx = fmaxf(mx, lj[j]);
  float sum = 0.f;
  #pragma unroll
  for (int j = 0; j < 18; ++j) sum += __expf(lj[j] - mx);
  const float ls = __logf(sum);
  const int a = acts[row];
  float tlp = 0.f, ent = 0.f;
  #pragma unroll
  for (int j = 0; j < 18; ++j) {
    const float lp = lj[j] - mx - ls;
    const float pj = __expf(lp);
    ent -= pj * lp;
    if (j == a) tlp = lp;
  }
  if (lane == 0) {
    out[row]         = tlp;
    out[10240 + row] = ent;
    out[20480 + row] = val;
  }
}

// ---------------- launch ----------------
extern "C" void kernel_launch(void* const* d_in, const int* in_sizes, int n_in,
                              void* d_out, int out_size, void* d_ws, size_t ws_size,
                              hipStream_t stream) {
  const float* obs  = (const float*)d_in[0];
  const float* mask = (const float*)d_in[1];
  const float* h0   = (const float*)d_in[2];
  const float* c0   = (const float*)d_in[3];
  const int*   acts = (const int*)d_in[4];
  const float* w1   = (const float*)d_in[5];
  const float* b1   = (const float*)d_in[6];
  const float* w2   = (const float*)d_in[7];
  const float* b2   = (const float*)d_in[8];
  const float* fcw  = (const float*)d_in[9];
  const float* fcb  = (const float*)d_in[10];
  const float* wih  = (const float*)d_in[11];
  const float* whh  = (const float*)d_in[12];
  const float* bih  = (const float*)d_in[13];
  const float* bhh  = (const float*)d_in[14];
  const float* vw   = (const float*)d_in[15];
  const float* vb   = (const float*)d_in[16];
  const float* lw   = (const float*)d_in[17];
  const float* lb   = (const float*)d_in[18];
  float* out = (float*)d_out;

  char* cur = (char*)d_ws;
  auto carve = [&](size_t bytes) {
    void* p = cur; cur += (bytes + 255) & ~(size_t)255; return p;
  };
  u16*   out2h = (u16*)carve(10240ULL * 2592 * 2);
  u16*   out2l = (u16*)carve(10240ULL * 2592 * 2);
  u16*   xh    = (u16*)carve(10240ULL * 256 * 2);
  u16*   xl    = (u16*)carve(10240ULL * 256 * 2);
  float* pre   = (float*)carve(10240ULL * 1024 * 4);
  float* hs    = (float*)carve(10240ULL * 256 * 4);
  u16*   w1h   = (u16*)carve(4096ULL * 2);
  u16*   w1l   = (u16*)carve(4096ULL * 2);
  u16*   w2h   = (u16*)carve(8192ULL * 2);
  u16*   w2l   = (u16*)carve(8192ULL * 2);
  u16*   fwh   = (u16*)carve(663552ULL * 2);
  u16*   fwl   = (u16*)carve(663552ULL * 2);
  u16*   iwh   = (u16*)carve(262144ULL * 2);
  u16*   iwl   = (u16*)carve(262144ULL * 2);
  u16*   whhh  = (u16*)carve(262144ULL * 2);
  float* bsum  = (float*)carve(1024ULL * 4);

  prep_k<<<512, 256, 0, stream>>>(w1, w2, fcw, wih, whh, bih, bhh,
                                  w1h, w1l, w2h, w2l, fwh, fwl, iwh, iwl, whhh, bsum);
  conv_k<<<7680, 256, 0, stream>>>(obs, w1h, w1l, b1, w2h, w2l, b2, out2h, out2l);
  gemm3_k<1, 1><<<160, 256, 0, stream>>>(out2h, out2l, fwh, fwl, fcb, xh, xl,
                                         10240, 256, 2592);
  gemm3_k<0, 0><<<640, 256, 0, stream>>>(xh, xl, iwh, iwl, bsum, pre, nullptr,
                                         10240, 1024, 256);
  lstm_k<<<128, 1024, 0, stream>>>(pre, mask, h0, c0, whhh, hs);
  heads_k<<<2560, 256, 0, stream>>>(hs, vw, vb, lw, lb, acts, out);
}

// Round 11
// 987.593 us; speedup vs baseline: 1.3403x; 1.1337x over previous
//
#include <hip/hip_runtime.h>

typedef unsigned short u16;
typedef unsigned int   u32;
typedef unsigned long long u64;
typedef short    s8v  __attribute__((ext_vector_type(8)));   // 8 x bf16 bits
typedef float    f4v  __attribute__((ext_vector_type(4)));
typedef u64      ul2v __attribute__((ext_vector_type(2)));
typedef _Float16 h2v  __attribute__((ext_vector_type(2)));

#define DEV __device__ __forceinline__

DEV u16 f2bf(float f) {                       // fp32 -> bf16 (round-half-up)
  u32 u = __builtin_bit_cast(u32, f);
  return (u16)((u + 0x8000u) >> 16);
}
DEV float bf2f(u16 b) { u32 u = ((u32)b) << 16; return __builtin_bit_cast(float, u); }
DEV void splitbf(float f, u16& hi, u16& lo) { // f ~= hi + lo (bf16 pair)
  hi = f2bf(f);
  lo = f2bf(f - bf2f(hi));
}
DEV u16 f2h(float f) {                        // fp32 -> fp16 bits (RNE)
  _Float16 h = (_Float16)f;
  return __builtin_bit_cast(u16, h);
}
DEV float h2f(u16 b) { _Float16 h = __builtin_bit_cast(_Float16, b); return (float)h; }
DEV float fdot2u(u32 a, u32 b, float c) {     // half2 dot + acc (fp32)
#if __has_builtin(__builtin_amdgcn_fdot2)
  return __builtin_amdgcn_fdot2(__builtin_bit_cast(h2v, a),
                                __builtin_bit_cast(h2v, b), c, false);
#else
  h2v x = __builtin_bit_cast(h2v, a), y = __builtin_bit_cast(h2v, b);
  return c + (float)x[0]*(float)y[0] + (float)x[1]*(float)y[1];
#endif
}
DEV float sigm(float x) { return 1.f / (1.f + __expf(-x)); }
DEV f4v mfma16(s8v a, s8v b, f4v c) {
  return __builtin_amdgcn_mfma_f32_16x16x32_bf16(a, b, c, 0, 0, 0);
}
DEV u32 permpack(u32 a, u32 b) {  // {a[31:16], b[31:16]}: b in low half
#if __has_builtin(__builtin_amdgcn_perm)
  return __builtin_amdgcn_perm(a, b, 0x07060302u);
#else
  return (b >> 16) | (a & 0xffff0000u);
#endif
}
// load 8 contiguous fp32 and split into hi/lo bf16 MFMA fragments.
// Rounding identical to splitbf (add 0x8000 then take high 16), but packing
// via v_perm_b32 (1 instr per pair per half) — ~10 VALU/pair vs ~14.
DEV void split8(const float* __restrict__ ap, s8v& Ah, s8v& Al) {
  const float4 v0 = *(const float4*)ap;
  const float4 v1 = *(const float4*)(ap + 4);
  const float f[8] = {v0.x, v0.y, v0.z, v0.w, v1.x, v1.y, v1.z, v1.w};
  uint4 hh, ll;
  u32 hp[4], lp[4];
  #pragma unroll
  for (int i = 0; i < 4; ++i) {
    const u32 ua = __builtin_bit_cast(u32, f[2 * i]);
    const u32 ub = __builtin_bit_cast(u32, f[2 * i + 1]);
    const u32 ta = ua + 0x8000u, tb = ub + 0x8000u;
    hp[i] = permpack(tb, ta);                       // hi pair
    const float la = f[2 * i]     - __builtin_bit_cast(float, ta & 0xffff0000u);
    const float lb = f[2 * i + 1] - __builtin_bit_cast(float, tb & 0xffff0000u);
    lp[i] = permpack(__builtin_bit_cast(u32, lb) + 0x8000u,
                     __builtin_bit_cast(u32, la) + 0x8000u);
  }
  hh.x = hp[0]; hh.y = hp[1]; hh.z = hp[2]; hh.w = hp[3];
  ll.x = lp[0]; ll.y = lp[1]; ll.z = lp[2]; ll.w = lp[3];
  Ah = __builtin_bit_cast(s8v, hh);
  Al = __builtin_bit_cast(s8v, ll);
}

// ---------------- prep: split-bf16 weight conversions ----------------
__global__ void prep_k(const float* __restrict__ w1, const float* __restrict__ w2,
                       const float* __restrict__ fcw, const float* __restrict__ wih,
                       const float* __restrict__ whh, const float* __restrict__ bih,
                       const float* __restrict__ bhh,
                       u16* __restrict__ w1h, u16* __restrict__ w1l,
                       u16* __restrict__ w2h, u16* __restrict__ w2l,
                       u16* __restrict__ fh,  u16* __restrict__ fl,
                       u16* __restrict__ ih,  u16* __restrict__ il,
                       u16* __restrict__ whhh, float* __restrict__ bsum) {
  const int i0 = blockIdx.x * 256 + threadIdx.x;
  const int st = gridDim.x * 256;
  for (int i = i0; i < 663552; i += st) splitbf(fcw[i], fh[i], fl[i]);
  for (int i = i0; i < 262144; i += st) splitbf(wih[i], ih[i], il[i]);
  for (int i = i0; i < 262144; i += st) whhh[i] = f2h(whh[i]);
  for (int i = i0; i < 4096;   i += st) splitbf(w1[i], w1h[i], w1l[i]);
  for (int i = i0; i < 8192;   i += st) {
    const int oc = i >> 8, k = i & 255;
    const int ky = k >> 6, kx = (k >> 4) & 3, cc = k & 15;   // k = ky*64+kx*16+c
    splitbf(w2[((oc * 16 + cc) * 4 + ky) * 4 + kx], w2h[i], w2l[i]);
  }
  for (int i = i0; i < 1024; i += st) bsum[i] = bih[i] + bhh[i];
}

// -------- fused conv1+conv2: lean LDS (25.6 KB), ONE barrier ----------
// Block = one image, 4 waves. conv1 reads obs DIRECT from global (R7/R10
// pattern: 8 contiguous aligned fp32/lane; R10 measured FETCH == compulsory
// 1.17 GB — L1/L2 fully absorb the 4x window overlap) and writes shared t1
// [400][16] hi/lo (un-padded, 25.6 KB -> 6 blocks/CU, 24 waves = 75% occ;
// R10's 41 KB -> 3 blocks/CU was the occupancy cap, VALUBusy 35% at 2.75
// waves/SIMD). ONE __syncthreads; with 6 co-resident blocks the barrier
// cannot idle the CU (R6-R9's barrier pathology was 1-block residency).
// conv2 reads t1 (8-way bank conflict at stride-16 — R10 measured this
// exact pattern at 1.38e7 conflict-cycles ~= 22us chip-wide, cheap vs +3
// waves/SIMD) and writes out2 direct to global.
__global__ __launch_bounds__(256) void conv_k(const float* __restrict__ obs,
    const u16* __restrict__ w1h, const u16* __restrict__ w1l, const float* __restrict__ b1,
    const u16* __restrict__ w2h, const u16* __restrict__ w2l, const float* __restrict__ b2,
    u16* __restrict__ out2h, u16* __restrict__ out2l) {
  __shared__ __align__(16) u16 t1h[6400], t1l[6400];  // [400 pos][16 oc]
  const int tid = threadIdx.x, lane = tid & 63, wid = tid >> 6;
  const int l15 = lane & 15, kc = lane >> 4;
  const int n = blockIdx.x;
  s8v bw1h[8], bw1l[8];                          // conv1 weights (64 VGPR)
  #pragma unroll
  for (int k0 = 0; k0 < 8; ++k0) {
    const int o1 = l15 * 256 + k0 * 32 + kc * 8;
    bw1h[k0] = *(const s8v*)(w1h + o1);
    bw1l[k0] = *(const s8v*)(w1l + o1);
  }
  const float bias1 = b1[l15];
  const float* img = obs + (u64)n * 28224;
  // conv1 (stride 4, 8x8): 25 chunks of 16 positions, waves interleave
  for (int ch = wid; ch < 25; ch += 4) {
    const int p = ch * 16 + l15;
    const int oy = p / 20, ox = p - oy * 20;
    const float* ab = img + oy * 336 + ox * 4;   // (4*oy)*84 + 4*ox
    f4v ahh = {0,0,0,0}, ahl = {0,0,0,0}, alh = {0,0,0,0};
    #pragma unroll
    for (int k0 = 0; k0 < 8; ++k0) {
      const int kb = k0 * 32 + kc * 8;           // k = c*64 + ky*8 + kx
      const int c = kb >> 6, ky = (kb >> 3) & 7;
      s8v Ah, Al;
      split8(ab + c * 7056 + ky * 84, Ah, Al);
      ahh = mfma16(Ah, bw1h[k0], ahh);
      ahl = mfma16(Ah, bw1l[k0], ahl);
      alh = mfma16(Al, bw1h[k0], alh);
    }
    const int pr0 = ch * 16 + kc * 4;
    #pragma unroll
    for (int r = 0; r < 4; ++r) {
      float v = fmaxf(ahh[r] + ahl[r] + alh[r] + bias1, 0.f);
      u16 hi, lo; splitbf(v, hi, lo);
      t1h[(pr0 + r) * 16 + l15] = hi;
      t1l[(pr0 + r) * 16 + l15] = lo;
    }
  }
  __syncthreads();                               // the only barrier
  // conv2 (stride 2, 4x4): 12 units (6 chunks x 2 oc-tiles) over 4 waves
  const float bb2a = b2[l15], bb2b = b2[16 + l15];
  for (int u = wid; u < 12; u += 4) {
    const int ch = u >> 1, ot = u & 1;           // ot fixed per wave-iter
    const int p = ch * 16 + l15;
    const int pc = p < 81 ? p : 80;
    const int oy = pc / 9, ox = pc - oy * 9;
    const int base = (oy * 40 + ox * 2) * 16;
    f4v a0 = {0,0,0,0}, a1 = {0,0,0,0}, a2 = {0,0,0,0};
    #pragma unroll
    for (int k0 = 0; k0 < 8; ++k0) {
      const int kb = k0 * 32 + kc * 8;           // k = ky*64 + kx*16 + c
      const int ky = kb >> 6, kx = (kb >> 4) & 3, c0 = kb & 15;
      const int off = base + (ky * 20 + kx) * 16 + c0;
      s8v Ah = *(const s8v*)(t1h + off);
      s8v Al = *(const s8v*)(t1l + off);
      const int wo = (ot * 16 + l15) * 256 + k0 * 32 + kc * 8;
      s8v Bh = *(const s8v*)(w2h + wo);
      s8v Bl = *(const s8v*)(w2l + wo);
      a0 = mfma16(Ah, Bh, a0);
      a1 = mfma16(Ah, Bl, a1);
      a2 = mfma16(Al, Bh, a2);
    }
    const float bb = ot ? bb2b : bb2a;
    const int oc = ot * 16 + l15;
    u16* dh = out2h + (u64)n * 2592 + oc * 81;
    u16* dl = out2l + (u64)n * 2592 + oc * 81;
    const int pr0 = ch * 16 + kc * 4;
    #pragma unroll
    for (int r = 0; r < 4; ++r) {
      const int pp = pr0 + r;
      if (pp < 81) {
        float v = fmaxf(a0[r] + a1[r] + a2[r] + bb, 0.f);
        u16 hi, lo; splitbf(v, hi, lo);
        dh[pp] = hi;
        dl[pp] = lo;
      }
    }
  }
}

// ------- split-bf16 GEMM: C = A(MxK) * B(NxK)^T, A~Ah+Al, B~Bh+Bl -------
// BM=BN=128, BK=32, 4 waves (2x2), each wave 64x64 via 4x4 16x16x32 MFMA
template <int RELU, int OSPLIT>
__global__ __launch_bounds__(256) void gemm3_k(const u16* __restrict__ Ah,
    const u16* __restrict__ Al, const u16* __restrict__ Bh, const u16* __restrict__ Bl,
    const float* __restrict__ bias, void* __restrict__ o1, void* __restrict__ o2,
    int M, int N, int K) {
  __shared__ __align__(16) u16 lAh[4096], lAl[4096];  // [128][32]
  __shared__ __align__(16) u16 lBh[4096], lBl[4096];  // [128][32]
  const int tid = threadIdx.x, lane = tid & 63, wid = tid >> 6;
  const int nb = N >> 7;
  const int bm = (int)blockIdx.x / nb, bn = (int)blockIdx.x % nb;
  const int m0 = bm << 7, n0 = bn << 7;
  const int wr = wid >> 1, wc = wid & 1;
  const int l15 = lane & 15, l4 = lane >> 4;
  f4v acc[4][4] = {};
  const int srow = tid >> 2;
  const int scol = (tid & 3) << 3;
  const u64 rA0 = (u64)(m0 + srow) * K + scol;
  const u64 rA1 = (u64)(m0 + 64 + srow) * K + scol;
  const u64 rB0 = (u64)(n0 + srow) * K + scol;
  const u64 rB1 = (u64)(n0 + 64 + srow) * K + scol;
  for (int k0 = 0; k0 < K; k0 += 32) {
    uint4 vah0 = *(const uint4*)(Ah + rA0 + k0);
    uint4 vah1 = *(const uint4*)(Ah + rA1 + k0);
    uint4 val0 = *(const uint4*)(Al + rA0 + k0);
    uint4 val1 = *(const uint4*)(Al + rA1 + k0);
    uint4 vbh0 = *(const uint4*)(Bh + rB0 + k0);
    uint4 vbh1 = *(const uint4*)(Bh + rB1 + k0);
    uint4 vbl0 = *(const uint4*)(Bl + rB0 + k0);
    uint4 vbl1 = *(const uint4*)(Bl + rB1 + k0);
    __syncthreads();
    ((uint4*)lAh)[tid] = vah0;  ((uint4*)lAh)[256 + tid] = vah1;
    ((uint4*)lAl)[tid] = val0;  ((uint4*)lAl)[256 + tid] = val1;
    ((uint4*)lBh)[tid] = vbh0;  ((uint4*)lBh)[256 + tid] = vbh1;
    ((uint4*)lBl)[tid] = vbl0;  ((uint4*)lBl)[256 + tid] = vbl1;
    __syncthreads();
    s8v afh[4], afl[4], bfh[4], bfl[4];
    #pragma unroll
    for (int a = 0; a < 4; ++a) {
      const int off = (wr * 64 + a * 16 + l15) * 32 + l4 * 8;
      afh[a] = *(const s8v*)(lAh + off);
      afl[a] = *(const s8v*)(lAl + off);
    }
    #pragma unroll
    for (int b = 0; b < 4; ++b) {
      const int off = (wc * 64 + b * 16 + l15) * 32 + l4 * 8;
      bfh[b] = *(const s8v*)(lBh + off);
      bfl[b] = *(const s8v*)(lBl + off);
    }
    #pragma unroll
    for (int a = 0; a < 4; ++a)
      #pragma unroll
      for (int b = 0; b < 4; ++b) {
        acc[a][b] = mfma16(afh[a], bfh[b], acc[a][b]);
        acc[a][b] = mfma16(afh[a], bfl[b], acc[a][b]);
        acc[a][b] = mfma16(afl[a], bfh[b], acc[a][b]);
      }
  }
  #pragma unroll
  for (int a = 0; a < 4; ++a) {
    const int mr = m0 + wr * 64 + a * 16 + l4 * 4;
    #pragma unroll
    for (int b = 0; b < 4; ++b) {
      const int col = n0 + wc * 64 + b * 16 + l15;
      const float bv = bias[col];
      #pragma unroll
      for (int r = 0; r < 4; ++r) {
        float v = acc[a][b][r] + bv;
        if (RELU) v = fmaxf(v, 0.f);
        const u64 idx = (u64)(mr + r) * N + col;
        if (OSPLIT) {
          u16 hi, lo; splitbf(v, hi, lo);
          ((u16*)o1)[idx] = hi;
          ((u16*)o2)[idx] = lo;
        } else {
          ((float*)o1)[idx] = v;
        }
      }
    }
  }
}

// ---------------- LSTM scan: 1 workgroup (1024 thr) per batch element ----
// thread (col=t&255, kq=t>>8) owns the K-QUARTER [kq*64, kq*64+64) of gate
// rows col (i), 256+col (f), 512+col (g) in VGPRs: 3 gates x 8 uint4 = 96
// VGPRs of weights — fits the 128-VGPR cap the compiler grants 1024-thread
// blocks (R4/R5 lesson: design to the cap instead of fighting it). o-gate
// rows in LDS chunk-transposed [kp4][col] (measured: 0 bank conflicts).
// h carried as fp16 hi+lo pair (fp32-grade). K-quarter partials reduced
// via 12 KB LDS. kq is wave-uniform -> divergence-free.
__global__ __launch_bounds__(1024) void lstm_k(const float* __restrict__ pre,
    const float* __restrict__ mask, const float* __restrict__ h0,
    const float* __restrict__ c0, const u16* __restrict__ whh,
    float* __restrict__ hs) {
  __shared__ __align__(16) uint4 lds_o[32 * 256];   // [kp4][col], 128 KB
  __shared__ __align__(16) float4 lds_red[3 * 256]; // kq=1..3 partials, 12 KB
  __shared__ __align__(16) u32 lds_hh[128];         // h hi (fp16 pairs)
  __shared__ __align__(16) u32 lds_hl[128];         // h lo
  const int t = threadIdx.x, b = blockIdx.x;
  const int col = t & 255, kq = t >> 8;             // kq wave-uniform
  // gate-row weights, K-quarter each: 8 uint4 per gate = 96 VGPRs total
  uint4 wi[8], wf[8], wg[8];
  {
    const u32* wb = (const u32*)whh;
    const uint4* pi_ = (const uint4*)(wb + (u64)col * 128) + kq * 8;
    const uint4* pf_ = (const uint4*)(wb + (u64)(256 + col) * 128) + kq * 8;
    const uint4* pg_ = (const uint4*)(wb + (u64)(512 + col) * 128) + kq * 8;
    #pragma unroll
    for (int q = 0; q < 8; ++q) {
      wi[q] = pi_[q]; wf[q] = pf_[q]; wg[q] = pg_[q];
    }
    // o-gate row quarter -> LDS chunk-transposed
    const uint4* po_ = (const uint4*)(wb + (u64)(768 + col) * 128);
    #pragma unroll
    for (int j = 0; j < 8; ++j) {
      const int kp4 = kq * 8 + j;
      lds_o[kp4 * 256 + col] = po_[kp4];
    }
  }
  float c = 0.f;
  if (kq == 0) c = c0[b * 256 + col];
  if (t < 128) {
    float a0 = h0[b * 256 + 2 * t], a1 = h0[b * 256 + 2 * t + 1];
    u16 h0a = f2h(a0); u16 l0a = f2h(a0 - h2f(h0a));
    u16 h1a = f2h(a1); u16 l1a = f2h(a1 - h2f(h1a));
    lds_hh[t] = (u32)h0a | ((u32)h1a << 16);
    lds_hl[t] = (u32)l0a | ((u32)l1a << 16);
  }
  float npi = 0.f, npf = 0.f, npg = 0.f, npo = 0.f;
  if (kq == 0) {                                    // prefetch step-0 pre
    const float* pr = pre + (u64)b * 1024;
    npi = pr[col]; npf = pr[256 + col]; npg = pr[512 + col]; npo = pr[768 + col];
  }
  __syncthreads();
  for (int s = 0; s < 80; ++s) {
    float ai = npi, afv = npf, ag = npg, ao = npo;  // kq!=0: zeros (partials)
    #pragma unroll
    for (int j = 0; j < 8; ++j) {
      const int kk = kq * 8 + j;
      const uint4 ov = lds_o[kk * 256 + col];       // conflict-free
      const uint4 hh = ((const uint4*)lds_hh)[kk];  // broadcast
      const uint4 hl = ((const uint4*)lds_hl)[kk];  // broadcast
      ai  = fdot2u(wi[j].x, hh.x, ai);  ai  = fdot2u(wi[j].y, hh.y, ai);
      ai  = fdot2u(wi[j].z, hh.z, ai);  ai  = fdot2u(wi[j].w, hh.w, ai);
      ai  = fdot2u(wi[j].x, hl.x, ai);  ai  = fdot2u(wi[j].y, hl.y, ai);
      ai  = fdot2u(wi[j].z, hl.z, ai);  ai  = fdot2u(wi[j].w, hl.w, ai);
      afv = fdot2u(wf[j].x, hh.x, afv); afv = fdot2u(wf[j].y, hh.y, afv);
      afv = fdot2u(wf[j].z, hh.z, afv); afv = fdot2u(wf[j].w, hh.w, afv);
      afv = fdot2u(wf[j].x, hl.x, afv); afv = fdot2u(wf[j].y, hl.y, afv);
      afv = fdot2u(wf[j].z, hl.z, afv); afv = fdot2u(wf[j].w, hl.w, afv);
      ag  = fdot2u(wg[j].x, hh.x, ag);  ag  = fdot2u(wg[j].y, hh.y, ag);
      ag  = fdot2u(wg[j].z, hh.z, ag);  ag  = fdot2u(wg[j].w, hh.w, ag);
      ag  = fdot2u(wg[j].x, hl.x, ag);  ag  = fdot2u(wg[j].y, hl.y, ag);
      ag  = fdot2u(wg[j].z, hl.z, ag);  ag  = fdot2u(wg[j].w, hl.w, ag);
      ao  = fdot2u(ov.x, hh.x, ao);     ao  = fdot2u(ov.y, hh.y, ao);
      ao  = fdot2u(ov.z, hh.z, ao);     ao  = fdot2u(ov.w, hh.w, ao);
      ao  = fdot2u(ov.x, hl.x, ao);     ao  = fdot2u(ov.y, hl.y, ao);
      ao  = fdot2u(ov.z, hl.z, ao);     ao  = fdot2u(ov.w, hl.w, ao);
    }
    if (kq != 0) {
      float4 r; r.x = ai; r.y = afv; r.z = ag; r.w = ao;
      lds_red[(kq - 1) * 256 + col] = r;
    } else if (s + 1 < 80) {                        // prefetch next-step pre
      const float* pr = pre + (u64)((s + 1) * 128 + b) * 1024;
      npi = pr[col]; npf = pr[256 + col]; npg = pr[512 + col]; npo = pr[768 + col];
    }
    __syncthreads();
    if (kq == 0) {
      const float4 r1 = lds_red[col];
      const float4 r2 = lds_red[256 + col];
      const float4 r3 = lds_red[512 + col];
      ai += r1.x + r2.x + r3.x;
      afv += r1.y + r2.y + r3.y;
      ag += r1.z + r2.z + r3.z;
      ao += r1.w + r2.w + r3.w;
      const float m = mask[s * 128 + b];
      const float ig = sigm(ai), fg = sigm(afv), og = sigm(ao);
      const float gg = tanhf(ag);
      const float cn = fg * c + ig * gg;
      const float hn = og * tanhf(cn);
      hs[(u64)(s * 128 + b) * 256 + col] = hn;      // unmasked output
      c = cn * m;
      const float hm = hn * m;                      // masked carry
      u16 hhi = f2h(hm);
      u16 hlo = f2h(hm - h2f(hhi));
      ((u16*)lds_hh)[col] = hhi;
      ((u16*)lds_hl)[col] = hlo;
    }
    __syncthreads();
  }
}

// ---------------- heads: value, log-softmax, entropy, action gather -------
__global__ __launch_bounds__(256) void heads_k(const float* __restrict__ hs,
    const float* __restrict__ vw, const float* __restrict__ vb,
    const float* __restrict__ lw, const float* __restrict__ lb,
    const int* __restrict__ acts, float* __restrict__ out) {
  const int lane = threadIdx.x & 63, wid = threadIdx.x >> 6;
  const int row = blockIdx.x * 4 + wid;
  const float4 h4 = *(const float4*)(hs + (u64)row * 256 + lane * 4);
  float lj[18];
  #pragma unroll
  for (int j = 0; j < 18; ++j) {
    const float4 w4 = *(const float4*)(lw + j * 256 + lane * 4);
    float p = h4.x * w4.x + h4.y * w4.y + h4.z * w4.z + h4.w * w4.w;
    #pragma unroll
    for (int o = 32; o > 0; o >>= 1) p += __shfl_xor(p, o, 64);
    lj[j] = p + lb[j];
  }
  const float4 v4 = *(const float4*)(vw + lane * 4);
  float val = h4.x * v4.x + h4.y * v4.y + h4.z * v4.z + h4.w * v4.w;
  #pragma unroll
  for (int o = 32; o > 0; o >>= 1) val += __shfl_xor(val, o, 64);
  val += vb[0];
  float mx = lj[0];
  #pragma unroll
  for (int j = 1; j < 18; ++j) mx = fmaxf(mx, lj[j]);
  float sum = 0.f;
  #pragma unroll
  for (int j = 0; j < 18; ++j) sum += __expf(lj[j] - mx);
  const float ls = __logf(sum);
  const int a = acts[row];
  float tlp = 0.f, ent = 0.f;
  #pragma unroll
  for (int j = 0; j < 18; ++j) {
    const float lp = lj[j] - mx - ls;
    const float pj = __expf(lp);
    ent -= pj * lp;
    if (j == a) tlp = lp;
  }
  if (lane == 0) {
    out[row]         = tlp;
    out[10240 + row] = ent;
    out[20480 + row] = val;
  }
}

// ---------------- launch ----------------
extern "C" void kernel_launch(void* const* d_in, const int* in_sizes, int n_in,
                              void* d_out, int out_size, void* d_ws, size_t ws_size,
                              hipStream_t stream) {
  const float* obs  = (const float*)d_in[0];
  const float* mask = (const float*)d_in[1];
  const float* h0   = (const float*)d_in[2];
  const float* c0   = (const float*)d_in[3];
  const int*   acts = (const int*)d_in[4];
  const float* w1   = (const float*)d_in[5];
  const float* b1   = (const float*)d_in[6];
  const float* w2   = (const float*)d_in[7];
  const float* b2   = (const float*)d_in[8];
  const float* fcw  = (const float*)d_in[9];
  const float* fcb  = (const float*)d_in[10];
  const float* wih  = (const float*)d_in[11];
  const float* whh  = (const float*)d_in[12];
  const float* bih  = (const float*)d_in[13];
  const float* bhh  = (const float*)d_in[14];
  const float* vw   = (const float*)d_in[15];
  const float* vb   = (const float*)d_in[16];
  const float* lw   = (const float*)d_in[17];
  const float* lb   = (const float*)d_in[18];
  float* out = (float*)d_out;

  char* cur = (char*)d_ws;
  auto carve = [&](size_t bytes) {
    void* p = cur; cur += (bytes + 255) & ~(size_t)255; return p;
  };
  u16*   out2h = (u16*)carve(10240ULL * 2592 * 2);
  u16*   out2l = (u16*)carve(10240ULL * 2592 * 2);
  u16*   xh    = (u16*)carve(10240ULL * 256 * 2);
  u16*   xl    = (u16*)carve(10240ULL * 256 * 2);
  float* pre   = (float*)carve(10240ULL * 1024 * 4);
  float* hs    = (float*)carve(10240ULL * 256 * 4);
  u16*   w1h   = (u16*)carve(4096ULL * 2);
  u16*   w1l   = (u16*)carve(4096ULL * 2);
  u16*   w2h   = (u16*)carve(8192ULL * 2);
  u16*   w2l   = (u16*)carve(8192ULL * 2);
  u16*   fwh   = (u16*)carve(663552ULL * 2);
  u16*   fwl   = (u16*)carve(663552ULL * 2);
  u16*   iwh   = (u16*)carve(262144ULL * 2);
  u16*   iwl   = (u16*)carve(262144ULL * 2);
  u16*   whhh  = (u16*)carve(262144ULL * 2);
  float* bsum  = (float*)carve(1024ULL * 4);

  prep_k<<<512, 256, 0, stream>>>(w1, w2, fcw, wih, whh, bih, bhh,
                                  w1h, w1l, w2h, w2l, fwh, fwl, iwh, iwl, whhh, bsum);
  conv_k<<<10240, 256, 0, stream>>>(obs, w1h, w1l, b1, w2h, w2l, b2, out2h, out2l);
  gemm3_k<1, 1><<<160, 256, 0, stream>>>(out2h, out2l, fwh, fwl, fcb, xh, xl,
                                         10240, 256, 2592);
  gemm3_k<0, 0><<<640, 256, 0, stream>>>(xh, xl, iwh, iwl, bsum, pre, nullptr,
                                         10240, 1024, 256);
  lstm_k<<<128, 1024, 0, stream>>>(pre, mask, h0, c0, whhh, hs);
  heads_k<<<2560, 256, 0, stream>>>(hs, vw, vb, lw, lb, acts, out);
}